// Round 4
// baseline (941.457 us; speedup 1.0000x reference)
//
#include <hip/hip_runtime.h>

#define N_      4096
#define D_      4096
#define H_      256
#define C_      16
#define NNZ_ATTR 262144
#define E_      131072
#define NNZ_JM  400000
#define NNZ_JA  80000
#define WORDS   128        // N_/32 words per bitmask row
#define ADJ_STRIDE 128     // max neighbors kept per row (col-deg ~Poisson(21), max ~50)

#define NB      1024       // main kernel grid: 4 blocks/CU x 256 CUs, co-resident
#define NT      256
#define GSIZE   (NB * NT)  // 262144

// ---------------- workspace layout (bytes) ----------------
#define OFF_JM   ((size_t)0)                        // 2 MB  jm bitmask [N][WORDS]
#define OFF_ABT  ((size_t)(2u<<20))                 // 2 MB  a_aug^T bitmask [N][WORDS]
#define OFF_CNT  ((size_t)(4u<<20))                 // 16 KB attr row counts
#define OFF_OFF  (OFF_CNT + (size_t)(32u<<10))      // row offsets (4097)
#define OFF_CUR  (OFF_CNT + (size_t)(64u<<10))      // scatter cursors
#define OFF_DINV (OFF_CNT + (size_t)(80u<<10))      // dinv
#define OFF_DEG  (OFF_CNT + (size_t)(96u<<10))      // row degree
#define OFF_CSR  (OFF_CNT + (size_t)(112u<<10))     // 1 MB  csr col indices
#define OFF_ADJ  (OFF_CSR + (size_t)(1u<<20))       // 2 MB  adjacency lists [N][128]
#define OFF_W1T  (OFF_ADJ + (size_t)(2u<<20))       // 4 MB  W1 transposed [D][H]
#define OFF_H1   (OFF_W1T + (size_t)(4u<<20))       // 4 MB  h1s = dinv[r]*h1[r]
#define OFF_H2   (OFF_H1  + (size_t)(4u<<20))       // 256 KB h2s = dinv[q]*h2[q]
#define OFF_BAR  (OFF_H2  + (size_t)(256u<<10))     // 128 B barrier state
#define ZERO_BYTES ((size_t)((4u<<20)+(16u<<10)))   // jm + abt + cnt (contiguous)
#define ZERO_U4    (ZERO_BYTES / 16)                // 263168 = 1028 * 256 exactly
#define ZB_BLOCKS  1028
#define TR_BLOCKS  1024

// ---------------- grid barrier (device-scope, sense via gen counter) ----------------
// bar[0] = arrive count, bar[1] = generation. Re-initialized by k_pre each launch.
__device__ __forceinline__ void gridbar(unsigned* bar) {
    __syncthreads();
    if (threadIdx.x == 0) {
        __threadfence();   // release: drain stores, write back local XCD L2
        unsigned g = __hip_atomic_load(&bar[1], __ATOMIC_ACQUIRE, __HIP_MEMORY_SCOPE_AGENT);
        unsigned a = __hip_atomic_fetch_add(&bar[0], 1u, __ATOMIC_ACQ_REL, __HIP_MEMORY_SCOPE_AGENT);
        if (a == (unsigned)(NB - 1)) {
            __hip_atomic_store(&bar[0], 0u, __ATOMIC_RELAXED, __HIP_MEMORY_SCOPE_AGENT);
            __hip_atomic_fetch_add(&bar[1], 1u, __ATOMIC_RELEASE, __HIP_MEMORY_SCOPE_AGENT);
        } else {
            while (__hip_atomic_load(&bar[1], __ATOMIC_ACQUIRE, __HIP_MEMORY_SCOPE_AGENT) == g)
                __builtin_amdgcn_s_sleep(4);
        }
        __threadfence();   // acquire: invalidate local L2 so we see other XCDs' writes
    }
    __syncthreads();
}

// ---------------- k_pre: zero jm/abt/cnt + transpose W1 + init barrier ----------------
__global__ void k_pre(const float* __restrict__ w1, float* __restrict__ w1t,
                      uint4* __restrict__ zp, unsigned* __restrict__ bar) {
    __shared__ float tile[32][33];
    int b = blockIdx.x, t = threadIdx.x;
    if (b == 0 && t < 2)
        __hip_atomic_store(&bar[t], 0u, __ATOMIC_RELAXED, __HIP_MEMORY_SCOPE_AGENT);
    if (b < ZB_BLOCKS) {
        zp[(size_t)b * NT + t] = make_uint4(0u, 0u, 0u, 0u);
    } else {
        int bb = b - ZB_BLOCKS;
        int gx = bb & 127, gy = bb >> 7;             // 128 x-tiles (D), 8 y-tiles (H)
        int tx = t & 31, ty = t >> 5;                // (32,8)
        int col = gx * 32 + tx;
        #pragma unroll
        for (int j = 0; j < 4; ++j)
            tile[ty + j * 8][tx] = w1[(size_t)(gy * 32 + ty + j * 8) * D_ + col];
        __syncthreads();
        int ocol = gy * 32 + tx;
        #pragma unroll
        for (int j = 0; j < 4; ++j)
            w1t[(size_t)(gx * 32 + ty + j * 8) * H_ + ocol] = tile[tx][ty + j * 8];
    }
}

// ---------------- k_main: all remaining phases, grid-barrier separated ----------------
__global__ void __launch_bounds__(NT, 4)
k_main(const int* __restrict__ attr_row, const int* __restrict__ attr_col,
       const int* __restrict__ edge, const int* __restrict__ jmsk,
       const int* __restrict__ jaug, const float* __restrict__ w2,
       const float* __restrict__ bias2, float* __restrict__ out,
       char* __restrict__ ws) {
    __shared__ __align__(16) char smem[5248];
    unsigned* jm   = (unsigned*)(ws + OFF_JM);
    unsigned* abt  = (unsigned*)(ws + OFF_ABT);
    unsigned* cnt  = (unsigned*)(ws + OFF_CNT);
    unsigned* roff = (unsigned*)(ws + OFF_OFF);
    unsigned* rcur = (unsigned*)(ws + OFF_CUR);
    float*    dinv = (float*)(ws + OFF_DINV);
    int*      deg  = (int*)(ws + OFF_DEG);
    unsigned* ccol = (unsigned*)(ws + OFF_CSR);
    int*      adj  = (int*)(ws + OFF_ADJ);
    float*    w1t  = (float*)(ws + OFF_W1T);
    float*    h1s  = (float*)(ws + OFF_H1);
    float*    h2s  = (float*)(ws + OFF_H2);
    unsigned* bar  = (unsigned*)(ws + OFF_BAR);

    const int b = blockIdx.x, t = threadIdx.x;
    const int gid = b * NT + t;

    // ---- P1: jm bitmask build + attr row histogram
    {
        const int* jr = jmsk;
        const int* jc = jmsk + NNZ_JM;
        for (int i = gid; i < NNZ_JM + NNZ_ATTR; i += GSIZE) {
            if (i < NNZ_JM) {
                int p = jr[i], q = jc[i];
                atomicOr(&jm[(size_t)p * WORDS + (q >> 5)], 1u << (q & 31));
            } else {
                atomicAdd(&cnt[attr_row[i - NNZ_JM]], 1u);
            }
        }
    }
    gridbar(bar);

    // ---- P2: a_aug^T bitmask (blocks 1..NB-1) | exclusive scan (block 0)
    {
        if (b == 0) {
            unsigned* s = (unsigned*)smem;
            unsigned v[16], sum = 0;
            int base = t * 16;
            #pragma unroll
            for (int k = 0; k < 16; ++k) { v[k] = cnt[base + k]; sum += v[k]; }
            s[t] = sum;
            __syncthreads();
            for (int d = 1; d < 256; d <<= 1) {
                unsigned x = 0;
                if (t >= d) x = s[t - d];
                __syncthreads();
                if (t >= d) s[t] += x;
                __syncthreads();
            }
            unsigned o = s[t] - sum;
            #pragma unroll
            for (int k = 0; k < 16; ++k) { roff[base + k] = o; rcur[base + k] = o; o += v[k]; }
            if (t == 255) roff[4096] = s[255];
        } else {
            const int* ep = edge;
            const int* eq = edge + E_;
            const int* jap = jaug;
            const int* jaq = jaug + NNZ_JA;
            for (int i = (b - 1) * NT + t; i < E_ + NNZ_JA + N_; i += (NB - 1) * NT) {
                if (i < E_) {
                    int p = ep[i], q = eq[i];
                    if ((jm[(size_t)p * WORDS + (q >> 5)] >> (q & 31)) & 1u)
                        atomicOr(&abt[(size_t)q * WORDS + (p >> 5)], 1u << (p & 31));
                } else if (i < E_ + NNZ_JA) {
                    int j2 = i - E_;
                    int p = jap[j2], q = jaq[j2];
                    atomicOr(&abt[(size_t)q * WORDS + (p >> 5)], 1u << (p & 31));
                } else {
                    int r = i - E_ - NNZ_JA;
                    atomicOr(&abt[(size_t)r * WORDS + (r >> 5)], 1u << (r & 31));
                }
            }
        }
    }
    gridbar(bar);

    // ---- P3: CSR scatter (1 item/thread, exact) + adj extraction (1 row/wave)
    {
        int r = attr_row[gid];
        unsigned pos = atomicAdd(&rcur[r], 1u);
        ccol[pos] = (unsigned)attr_col[gid];

        int wv = t >> 6, lane = t & 63;
        int q = b * 4 + wv;
        const unsigned* row = abt + (size_t)q * WORDS;
        unsigned w0 = row[2 * lane], w1b = row[2 * lane + 1];
        int c = __popc(w0) + __popc(w1b);
        int pre = c;
        #pragma unroll
        for (int d2 = 1; d2 < 64; d2 <<= 1) {
            int x = __shfl_up(pre, d2);
            if (lane >= d2) pre += x;
        }
        int excl = pre - c;
        int total = __shfl(pre, 63);
        if (lane == 0) {
            dinv[q] = rsqrtf((float)total);
            deg[q] = total < ADJ_STRIDE ? total : ADJ_STRIDE;
        }
        unsigned idx = (unsigned)excl;
        int* arow = adj + (size_t)q * ADJ_STRIDE;
        int base0 = lane * 64;
        while (w0)  { int bp = __ffs(w0) - 1;  w0  &= w0 - 1;  if (idx < ADJ_STRIDE) arow[idx] = base0 + bp;      ++idx; }
        while (w1b) { int bp = __ffs(w1b) - 1; w1b &= w1b - 1; if (idx < ADJ_STRIDE) arow[idx] = base0 + 32 + bp; ++idx; }
    }
    gridbar(bar);

    // ---- P4: h1s[r,:] = dinv[r] * sum_{c in row r} W1T[c,:]   (4 rows/block)
    {
        unsigned* cols = (unsigned*)smem;          // 256 u32
        float* part = (float*)(smem + 1024);       // [4][64][4] f32
        int g = t >> 6, lane = t & 63;
        for (int r = b; r < N_; r += NB) {
            unsigned beg = roff[r], end = roff[r + 1];
            float4 acc = make_float4(0.f, 0.f, 0.f, 0.f);
            for (unsigned base = beg; base < end; base += 256) {
                unsigned m = min(256u, end - base);
                __syncthreads();
                if ((unsigned)t < m) cols[t] = ccol[base + t];
                __syncthreads();
                unsigned j = (unsigned)g;
                for (; j + 12 < m; j += 16) {
                    unsigned c0 = cols[j], c1 = cols[j + 4], c2 = cols[j + 8], c3 = cols[j + 12];
                    float4 v0 = *(const float4*)&w1t[(size_t)c0 * H_ + lane * 4];
                    float4 v1 = *(const float4*)&w1t[(size_t)c1 * H_ + lane * 4];
                    float4 v2 = *(const float4*)&w1t[(size_t)c2 * H_ + lane * 4];
                    float4 v3 = *(const float4*)&w1t[(size_t)c3 * H_ + lane * 4];
                    acc.x += v0.x + v1.x + v2.x + v3.x;
                    acc.y += v0.y + v1.y + v2.y + v3.y;
                    acc.z += v0.z + v1.z + v2.z + v3.z;
                    acc.w += v0.w + v1.w + v2.w + v3.w;
                }
                for (; j < m; j += 4) {
                    unsigned c0 = cols[j];
                    float4 v0 = *(const float4*)&w1t[(size_t)c0 * H_ + lane * 4];
                    acc.x += v0.x; acc.y += v0.y; acc.z += v0.z; acc.w += v0.w;
                }
            }
            ((float4*)part)[g * 64 + lane] = acc;
            __syncthreads();
            int comp = t & 3, idx4 = t >> 2;
            float s0 = part[(0 * 64 + idx4) * 4 + comp];
            float s1 = part[(1 * 64 + idx4) * 4 + comp];
            float s2 = part[(2 * 64 + idx4) * 4 + comp];
            float s3 = part[(3 * 64 + idx4) * 4 + comp];
            h1s[(size_t)r * H_ + t] = (s0 + s1 + s2 + s3) * dinv[r];
            __syncthreads();
        }
    }
    gridbar(bar);

    // ---- P5: out1 = relu(dinv[q]*sum adj h1s); h2s = dinv[q]*(out1 @ W2^T)  (4 rows/block)
    {
        int* adj_s = (int*)smem;                        // 128 i32
        float* hrow = (float*)(smem + 512);             // 256 f32
        float* partial = (float*)(smem + 512 + 1024);   // [16][17] f32
        int c = t & 15, g = t >> 4;
        float w2r[16];
        #pragma unroll
        for (int kk = 0; kk < 16; ++kk) w2r[kk] = w2[(size_t)c * H_ + g * 16 + kk];
        for (int q = b; q < N_; q += NB) {
            __syncthreads();
            if (t < ADJ_STRIDE) adj_s[t] = adj[(size_t)q * ADJ_STRIDE + t];
            __syncthreads();
            int dg = deg[q];
            float acc = 0.f;
            int j = 0;
            for (; j + 4 <= dg; j += 4) {
                int p0 = adj_s[j], p1 = adj_s[j + 1], p2 = adj_s[j + 2], p3 = adj_s[j + 3];
                acc += h1s[(size_t)p0 * H_ + t] + h1s[(size_t)p1 * H_ + t]
                     + h1s[(size_t)p2 * H_ + t] + h1s[(size_t)p3 * H_ + t];
            }
            for (; j < dg; ++j) acc += h1s[(size_t)adj_s[j] * H_ + t];
            float dq = dinv[q];
            hrow[t] = fmaxf(acc * dq, 0.f);
            __syncthreads();
            float part = 0.f;
            #pragma unroll
            for (int kk = 0; kk < 16; ++kk) part += hrow[g * 16 + kk] * w2r[kk];
            partial[g * 17 + c] = part;
            __syncthreads();
            if (t < 16) {
                float s = 0.f;
                #pragma unroll
                for (int g2 = 0; g2 < 16; ++g2) s += partial[g2 * 17 + t];
                h2s[(size_t)q * C_ + t] = s * dq;
            }
        }
    }
    gridbar(bar);

    // ---- P6: out[q,c] = dinv[q] * sum adj h2s[p,c] + bias[c]  (1 row/wave, 4-way split)
    {
        int wv = t >> 6, lane = t & 63;
        int q = b * 4 + wv;
        int c = lane & 15, prt = lane >> 4;
        int dg = deg[q];
        const int* arow = adj + (size_t)q * ADJ_STRIDE;
        float acc = 0.f;
        for (int j = prt; j < dg; j += 4)
            acc += h2s[(size_t)arow[j] * C_ + c];
        acc += __shfl_down(acc, 32);
        acc += __shfl_down(acc, 16);
        if (lane < 16)
            out[(size_t)q * C_ + c] = dinv[q] * acc + bias2[c];
    }
}

// ---------------- launch ----------------

extern "C" void kernel_launch(void* const* d_in, const int* in_sizes, int n_in,
                              void* d_out, int out_size, void* d_ws, size_t ws_size,
                              hipStream_t stream) {
    const int*   attr_row = (const int*)d_in[0];
    const int*   attr_col = (const int*)d_in[1];
    const int*   edge     = (const int*)d_in[2];   // [2][E_]
    const int*   jmsk     = (const int*)d_in[3];   // [2][NNZ_JM]
    const int*   jaug     = (const int*)d_in[4];   // [2][NNZ_JA]
    const float* w1       = (const float*)d_in[5]; // [H_][D_]
    const float* w2       = (const float*)d_in[6]; // [C_][H_]
    const float* bias2    = (const float*)d_in[7]; // [C_]
    float*       out      = (float*)d_out;

    char* ws = (char*)d_ws;
    float*    w1t = (float*)(ws + OFF_W1T);
    unsigned* bar = (unsigned*)(ws + OFF_BAR);

    k_pre<<<ZB_BLOCKS + TR_BLOCKS, NT, 0, stream>>>(w1, w1t, (uint4*)d_ws, bar);
    k_main<<<NB, NT, 0, stream>>>(attr_row, attr_col, edge, jmsk, jaug,
                                  w2, bias2, out, ws);
}

// Round 5
// 603.975 us; speedup vs baseline: 1.5588x; 1.5588x over previous
//
#include <hip/hip_runtime.h>

#define N_      4096
#define D_      4096
#define H_      256
#define C_      16
#define NNZ_ATTR 262144
#define E_      131072
#define NNZ_JM  400000
#define NNZ_JA  80000
#define WORDS   128        // N_/32 words per bitmask row
#define ADJ_STRIDE 128     // max neighbors kept per row (col-deg ~21 avg)
#define ASTR    128        // attr cols per row cap (mean 64, 8 sigma)

#define NB      1024       // 4 blocks/CU x 256 CUs, co-resident by construction
#define NT      256
#define GSIZE   (NB * NT)  // 262144

// ---------------- workspace layout (bytes), total ~14.3 MB ----------------
#define OFF_JM   ((size_t)0)                        // 2 MB  jm bitmask (dead after P2; reused as adj)
#define OFF_ABT  ((size_t)(2u<<20))                 // 2 MB  a_aug^T bitmask
#define OFF_CNT  ((size_t)(4u<<20))                 // 16 KB attr row counts
#define OFF_BAR  (OFF_CNT + (size_t)(16u<<10))      // 128 B barrier state
#define OFF_DINV (OFF_CNT + (size_t)(32u<<10))      // 16 KB dinv
#define OFF_DEG  (OFF_CNT + (size_t)(48u<<10))      // 16 KB adj degree
#define OFF_CCOL (OFF_CNT + (size_t)(64u<<10))      // 2 MB  attr col slots [N][ASTR]
#define OFF_W1T  (OFF_CCOL + (size_t)(2u<<20))      // 4 MB  W1 transposed [D][H]
#define OFF_H1   (OFF_W1T + (size_t)(4u<<20))       // 4 MB  h1s = dinv[r]*h1[r]
#define OFF_H2   (OFF_H1  + (size_t)(4u<<20))       // 256 KB h2s
#define OFF_ADJ  OFF_JM                             // 2 MB  adjacency lists [N][128]
#define ZERO_BYTES ((size_t)((4u<<20)+(16u<<10)))   // jm + abt + cnt (contiguous)
#define ZB_BLOCKS  1028                             // ZERO_BYTES/16/256 exactly
#define TR_BLOCKS  1024

// ---------------- grid barrier ----------------
// bar[0]=arrive count, bar[1]=generation; re-inited by k_pre each launch.
// KEY FIX vs round 4: the spin loop uses RELAXED loads (no per-poll L2
// invalidate); exactly one __threadfence() on each side of the barrier.
// The RELEASE on the arrival fetch_add also keeps the prior gen-read from
// sinking below it (prevents a lost-generation hang).
__device__ __forceinline__ void gridbar(unsigned* bar) {
    __syncthreads();
    if (threadIdx.x == 0) {
        __threadfence();   // release: write back this block's stores
        unsigned g = __hip_atomic_load(&bar[1], __ATOMIC_RELAXED, __HIP_MEMORY_SCOPE_AGENT);
        unsigned a = __hip_atomic_fetch_add(&bar[0], 1u, __ATOMIC_RELEASE, __HIP_MEMORY_SCOPE_AGENT);
        if (a == (unsigned)(NB - 1)) {
            __hip_atomic_store(&bar[0], 0u, __ATOMIC_RELAXED, __HIP_MEMORY_SCOPE_AGENT);
            __hip_atomic_store(&bar[1], g + 1u, __ATOMIC_RELEASE, __HIP_MEMORY_SCOPE_AGENT);
        } else {
            while (__hip_atomic_load(&bar[1], __ATOMIC_RELAXED, __HIP_MEMORY_SCOPE_AGENT) == g)
                __builtin_amdgcn_s_sleep(8);
        }
        __threadfence();   // acquire: invalidate so we see other XCDs' writes
    }
    __syncthreads();
}

// ---------------- k_pre: zero jm/abt/cnt + init barrier + transpose W1 ----------------
__global__ void k_pre(const float* __restrict__ w1, float* __restrict__ w1t,
                      uint4* __restrict__ zp, unsigned* __restrict__ bar) {
    __shared__ float tile[32][33];
    int b = blockIdx.x, t = threadIdx.x;
    if (b == 0 && t < 2)
        __hip_atomic_store(&bar[t], 0u, __ATOMIC_RELAXED, __HIP_MEMORY_SCOPE_AGENT);
    if (b < ZB_BLOCKS) {
        zp[(size_t)b * NT + t] = make_uint4(0u, 0u, 0u, 0u);
    } else {
        int bb = b - ZB_BLOCKS;
        int gx = bb & 127, gy = bb >> 7;             // 128 D-tiles, 8 H-tiles
        int tx = t & 31, ty = t >> 5;                // (32,8)
        int col = gx * 32 + tx;
        #pragma unroll
        for (int j = 0; j < 4; ++j)
            tile[ty + j * 8][tx] = w1[(size_t)(gy * 32 + ty + j * 8) * D_ + col];
        __syncthreads();
        int ocol = gy * 32 + tx;
        #pragma unroll
        for (int j = 0; j < 4; ++j)
            w1t[(size_t)(gx * 32 + ty + j * 8) * H_ + ocol] = tile[tx][ty + j * 8];
    }
}

// ---------------- k_main: 5 phases, 4 grid barriers ----------------
__global__ void __launch_bounds__(NT, 4)
k_main(const int* __restrict__ attr_row, const int* __restrict__ attr_col,
       const int* __restrict__ edge, const int* __restrict__ jmsk,
       const int* __restrict__ jaug, const float* __restrict__ w2,
       const float* __restrict__ bias2, float* __restrict__ out,
       char* __restrict__ ws) {
    __shared__ __align__(16) char smem[4608];
    unsigned* jm   = (unsigned*)(ws + OFF_JM);
    unsigned* abt  = (unsigned*)(ws + OFF_ABT);
    unsigned* cnt  = (unsigned*)(ws + OFF_CNT);
    float*    dinv = (float*)(ws + OFF_DINV);
    int*      deg  = (int*)(ws + OFF_DEG);
    unsigned* ccol = (unsigned*)(ws + OFF_CCOL);
    int*      adj  = (int*)(ws + OFF_ADJ);      // overlays jm (dead after P2)
    float*    w1t  = (float*)(ws + OFF_W1T);
    float*    h1s  = (float*)(ws + OFF_H1);
    float*    h2s  = (float*)(ws + OFF_H2);
    unsigned* bar  = (unsigned*)(ws + OFF_BAR);

    const int b = blockIdx.x, t = threadIdx.x;
    const int gid = b * NT + t;

    // ---- P1: jm bitmask build + attr scatter into fixed-stride slots
    {
        const int* jr = jmsk;
        const int* jc = jmsk + NNZ_JM;
        for (int i = gid; i < NNZ_JM + NNZ_ATTR; i += GSIZE) {
            if (i < NNZ_JM) {
                int p = jr[i], q = jc[i];
                atomicOr(&jm[(size_t)p * WORDS + (q >> 5)], 1u << (q & 31));
            } else {
                int j = i - NNZ_JM;
                int r = attr_row[j];
                unsigned pos = atomicAdd(&cnt[r], 1u);
                if (pos < ASTR) ccol[(size_t)r * ASTR + pos] = (unsigned)attr_col[j];
            }
        }
    }
    gridbar(bar);

    // ---- P2: a_aug^T bitmask build (edges&jm, ja, diagonal)
    {
        if (gid < E_) {
            int p = edge[gid], q = edge[E_ + gid];
            if ((jm[(size_t)p * WORDS + (q >> 5)] >> (q & 31)) & 1u)
                atomicOr(&abt[(size_t)q * WORDS + (p >> 5)], 1u << (p & 31));
        } else if (gid < E_ + NNZ_JA) {
            int j = gid - E_;
            int p = jaug[j], q = jaug[NNZ_JA + j];
            atomicOr(&abt[(size_t)q * WORDS + (p >> 5)], 1u << (p & 31));
        } else if (gid < E_ + NNZ_JA + N_) {
            int r = gid - E_ - NNZ_JA;
            atomicOr(&abt[(size_t)r * WORDS + (r >> 5)], 1u << (r & 31));
        }
    }
    gridbar(bar);

    // ---- P34: adj/dinv/deg extraction for rows 4b..4b+3 (1 row/wave),
    //          then h1s for the SAME rows (dinv is block-local -> no grid barrier)
    {
        unsigned* cols = (unsigned*)smem;            // 128 u32 (512 B)
        float* part = (float*)(smem + 512);          // [4][64][4] f32 (4096 B)
        int wv = t >> 6, lane = t & 63;
        int q = 4 * b + wv;
        {
            const unsigned* rowp = abt + (size_t)q * WORDS;
            unsigned w0 = rowp[2 * lane], w1b = rowp[2 * lane + 1];
            int c = __popc(w0) + __popc(w1b);
            int pre = c;
            #pragma unroll
            for (int d2 = 1; d2 < 64; d2 <<= 1) {
                int x = __shfl_up(pre, d2);
                if (lane >= d2) pre += x;
            }
            int excl = pre - c;
            int total = __shfl(pre, 63);
            if (lane == 0) {
                dinv[q] = rsqrtf((float)total);
                deg[q] = total < ADJ_STRIDE ? total : ADJ_STRIDE;
            }
            unsigned idx = (unsigned)excl;
            int* arow = adj + (size_t)q * ADJ_STRIDE;
            int base0 = lane * 64;
            while (w0)  { int bp = __ffs(w0) - 1;  w0  &= w0 - 1;  if (idx < ADJ_STRIDE) arow[idx] = base0 + bp;      ++idx; }
            while (w1b) { int bp = __ffs(w1b) - 1; w1b &= w1b - 1; if (idx < ADJ_STRIDE) arow[idx] = base0 + 32 + bp; ++idx; }
        }
        __syncthreads();
        int g = t >> 6;
        for (int i = 0; i < 4; ++i) {
            int r = 4 * b + i;
            unsigned m = min(cnt[r], (unsigned)ASTR);
            if ((unsigned)t < m) cols[t] = ccol[(size_t)r * ASTR + t];
            __syncthreads();
            float4 acc = make_float4(0.f, 0.f, 0.f, 0.f);
            unsigned j = (unsigned)g;
            for (; j + 12 < m; j += 16) {
                unsigned c0 = cols[j], c1 = cols[j + 4], c2 = cols[j + 8], c3 = cols[j + 12];
                float4 v0 = *(const float4*)&w1t[(size_t)c0 * H_ + lane * 4];
                float4 v1 = *(const float4*)&w1t[(size_t)c1 * H_ + lane * 4];
                float4 v2 = *(const float4*)&w1t[(size_t)c2 * H_ + lane * 4];
                float4 v3 = *(const float4*)&w1t[(size_t)c3 * H_ + lane * 4];
                acc.x += v0.x + v1.x + v2.x + v3.x;
                acc.y += v0.y + v1.y + v2.y + v3.y;
                acc.z += v0.z + v1.z + v2.z + v3.z;
                acc.w += v0.w + v1.w + v2.w + v3.w;
            }
            for (; j < m; j += 4) {
                unsigned c0 = cols[j];
                float4 v0 = *(const float4*)&w1t[(size_t)c0 * H_ + lane * 4];
                acc.x += v0.x; acc.y += v0.y; acc.z += v0.z; acc.w += v0.w;
            }
            ((float4*)part)[g * 64 + lane] = acc;
            __syncthreads();
            int comp = t & 3, idx4 = t >> 2;
            float s0 = part[(0 * 64 + idx4) * 4 + comp];
            float s1 = part[(1 * 64 + idx4) * 4 + comp];
            float s2 = part[(2 * 64 + idx4) * 4 + comp];
            float s3 = part[(3 * 64 + idx4) * 4 + comp];
            h1s[(size_t)r * H_ + t] = (s0 + s1 + s2 + s3) * dinv[r];
            __syncthreads();
        }
    }
    gridbar(bar);

    // ---- P5: out1 = relu(dinv[q]*sum_adj h1s); h2s = dinv[q]*(out1 @ W2^T)
    {
        int* adj_s = (int*)smem;                        // 128 i32
        float* hrow = (float*)(smem + 512);             // 256 f32
        float* partial = (float*)(smem + 512 + 1024);   // [16][17] f32
        int c = t & 15, g = t >> 4;
        float w2r[16];
        #pragma unroll
        for (int kk = 0; kk < 16; ++kk) w2r[kk] = w2[(size_t)c * H_ + g * 16 + kk];
        for (int i = 0; i < 4; ++i) {
            int q = 4 * b + i;
            __syncthreads();
            if (t < ADJ_STRIDE) adj_s[t] = adj[(size_t)q * ADJ_STRIDE + t];
            __syncthreads();
            int dg = deg[q];
            float acc = 0.f;
            int j = 0;
            for (; j + 4 <= dg; j += 4) {
                int p0 = adj_s[j], p1 = adj_s[j + 1], p2 = adj_s[j + 2], p3 = adj_s[j + 3];
                acc += h1s[(size_t)p0 * H_ + t] + h1s[(size_t)p1 * H_ + t]
                     + h1s[(size_t)p2 * H_ + t] + h1s[(size_t)p3 * H_ + t];
            }
            for (; j < dg; ++j) acc += h1s[(size_t)adj_s[j] * H_ + t];
            float dq = dinv[q];
            hrow[t] = fmaxf(acc * dq, 0.f);
            __syncthreads();
            float part = 0.f;
            #pragma unroll
            for (int kk = 0; kk < 16; ++kk) part += hrow[g * 16 + kk] * w2r[kk];
            partial[g * 17 + c] = part;
            __syncthreads();
            if (t < 16) {
                float s = 0.f;
                #pragma unroll
                for (int g2 = 0; g2 < 16; ++g2) s += partial[g2 * 17 + t];
                h2s[(size_t)q * C_ + t] = s * dq;
            }
        }
    }
    gridbar(bar);

    // ---- P6: out[q,c] = dinv[q] * sum_adj h2s[p,c] + bias[c]  (1 row/wave)
    {
        int wv = t >> 6, lane = t & 63;
        int q = 4 * b + wv;
        int c = lane & 15, prt = lane >> 4;
        int dg = deg[q];
        const int* arow = adj + (size_t)q * ADJ_STRIDE;
        float acc = 0.f;
        for (int j = prt; j < dg; j += 4)
            acc += h2s[(size_t)arow[j] * C_ + c];
        acc += __shfl_down(acc, 32);
        acc += __shfl_down(acc, 16);
        if (lane < 16)
            out[(size_t)q * C_ + c] = dinv[q] * acc + bias2[c];
    }
}

// ---------------- launch ----------------

extern "C" void kernel_launch(void* const* d_in, const int* in_sizes, int n_in,
                              void* d_out, int out_size, void* d_ws, size_t ws_size,
                              hipStream_t stream) {
    const int*   attr_row = (const int*)d_in[0];
    const int*   attr_col = (const int*)d_in[1];
    const int*   edge     = (const int*)d_in[2];   // [2][E_]
    const int*   jmsk     = (const int*)d_in[3];   // [2][NNZ_JM]
    const int*   jaug     = (const int*)d_in[4];   // [2][NNZ_JA]
    const float* w1       = (const float*)d_in[5]; // [H_][D_]
    const float* w2       = (const float*)d_in[6]; // [C_][H_]
    const float* bias2    = (const float*)d_in[7]; // [C_]
    float*       out      = (float*)d_out;

    char* ws = (char*)d_ws;
    float*    w1t = (float*)(ws + OFF_W1T);
    unsigned* bar = (unsigned*)(ws + OFF_BAR);

    k_pre<<<ZB_BLOCKS + TR_BLOCKS, NT, 0, stream>>>(w1, w1t, (uint4*)d_ws, bar);
    k_main<<<NB, NT, 0, stream>>>(attr_row, attr_col, edge, jmsk, jaug,
                                  w2, bias2, out, ws);
}

// Round 6
// 214.063 us; speedup vs baseline: 4.3980x; 2.8215x over previous
//
#include <hip/hip_runtime.h>

#define N_      4096
#define D_      4096
#define H_      256
#define C_      16
#define NNZ_ATTR 262144
#define E_      131072
#define NNZ_JM  400000
#define NNZ_JA  80000
#define WORDS   128        // N_/32 words per bitmask row
#define ADJ_STRIDE 128     // max neighbors kept per row (col-deg ~21 avg, max ~45)
#define ASTR    128        // attr cols per row cap (mean 64, 8 sigma)

#define NB      1024       // 4 blocks/CU x 256 CUs, co-resident by construction
#define NT      256
#define GSIZE   (NB * NT)
#define NLEAF   32         // barrier tree fanout
#define LEAF_BLKS (NB / NLEAF)   // 32 blocks per leaf

// ---------------- workspace layout (bytes), ~18.3 MB ----------------
#define OFF_EBT  ((size_t)0)                        // 2 MB  edge bitmask transposed [q][p]
#define OFF_JMT  ((size_t)(2u<<20))                 // 2 MB  jm bitmask transposed
#define OFF_JAT  ((size_t)(4u<<20))                 // 2 MB  ja bitmask transposed
#define OFF_CNT  ((size_t)(6u<<20))                 // 16 KB attr row counts
#define OFF_BAR  (OFF_CNT + (size_t)(16u<<10))      // 16 KB barrier tree state
#define OFF_DINV (OFF_CNT + (size_t)(32u<<10))      // 16 KB dinv
#define OFF_DEG  (OFF_CNT + (size_t)(48u<<10))      // 16 KB adj degree
#define OFF_CCOL (OFF_CNT + (size_t)(64u<<10))      // 2 MB  attr col slots [N][ASTR]
#define OFF_ADJ  (OFF_CCOL + (size_t)(2u<<20))      // 2 MB  adjacency lists [N][128]
#define OFF_W1T  (OFF_ADJ + (size_t)(2u<<20))       // 4 MB  W1 transposed [D][H]
#define OFF_H1   (OFF_W1T + (size_t)(4u<<20))       // 4 MB  h1s = dinv[r]*h1[r]
#define OFF_H2   (OFF_H1  + (size_t)(4u<<20))       // 256 KB h2s

#define ZERO_BYTES (OFF_BAR + (size_t)(16u<<10))    // ebt+jmt+jat+cnt+bar = 6324224
#define ZB_BLOCKS  1544                             // ZERO_BYTES / (256*16) exactly
#define TR_BLOCKS  1024

// barrier state u32 indices (each slot in its own 128-B line):
// leafcnt[l] @ l*32 | rootcnt @ 1024 | gen @ 1056 | leafgen[l] @ 1088 + l*32

// ---------------- tree grid barrier ----------------
// Monotonic phase-tagged tickets: no resets, no pre-reads -> no reorder hazard,
// deadlock-free (all waits are on monotonically increasing values).
// Contention per line <= 32 RMWs or ~31 slow pollers (128-B separated lines).
__device__ __forceinline__ void gridbar(unsigned* bs, unsigned phase) {
    __syncthreads();
    if (threadIdx.x == 0) {
        __threadfence();   // release: write back local XCD L2
        int leaf = blockIdx.x & (NLEAF - 1);
        unsigned tk = __hip_atomic_fetch_add(&bs[leaf * 32], 1u,
                          __ATOMIC_RELAXED, __HIP_MEMORY_SCOPE_AGENT);
        if (tk == phase * LEAF_BLKS - 1) {
            // leaf closer: arrive at root, wait for gen, relay to leaf line
            unsigned rt = __hip_atomic_fetch_add(&bs[1024], 1u,
                              __ATOMIC_RELAXED, __HIP_MEMORY_SCOPE_AGENT);
            if (rt == phase * NLEAF - 1) {
                __hip_atomic_store(&bs[1056], phase,
                                   __ATOMIC_RELAXED, __HIP_MEMORY_SCOPE_AGENT);
            } else {
                while (__hip_atomic_load(&bs[1056], __ATOMIC_RELAXED,
                                         __HIP_MEMORY_SCOPE_AGENT) < phase)
                    __builtin_amdgcn_s_sleep(16);
            }
            __hip_atomic_store(&bs[1088 + leaf * 32], phase,
                               __ATOMIC_RELAXED, __HIP_MEMORY_SCOPE_AGENT);
        } else {
            while (__hip_atomic_load(&bs[1088 + leaf * 32], __ATOMIC_RELAXED,
                                     __HIP_MEMORY_SCOPE_AGENT) < phase)
                __builtin_amdgcn_s_sleep(16);
        }
        __threadfence();   // acquire: invalidate local L2
    }
    __syncthreads();
}

// ---------------- k_pre: zero masks/cnt/barrier + transpose W1 ----------------
__global__ void k_pre(const float* __restrict__ w1, float* __restrict__ w1t,
                      uint4* __restrict__ zp) {
    __shared__ float tile[32][33];
    int b = blockIdx.x, t = threadIdx.x;
    if (b < ZB_BLOCKS) {
        zp[(size_t)b * NT + t] = make_uint4(0u, 0u, 0u, 0u);
    } else {
        int bb = b - ZB_BLOCKS;
        int gx = bb & 127, gy = bb >> 7;             // 128 D-tiles, 8 H-tiles
        int tx = t & 31, ty = t >> 5;                // (32,8)
        int col = gx * 32 + tx;
        #pragma unroll
        for (int j = 0; j < 4; ++j)
            tile[ty + j * 8][tx] = w1[(size_t)(gy * 32 + ty + j * 8) * D_ + col];
        __syncthreads();
        int ocol = gy * 32 + tx;
        #pragma unroll
        for (int j = 0; j < 4; ++j)
            w1t[(size_t)(gx * 32 + ty + j * 8) * H_ + ocol] = tile[tx][ty + j * 8];
    }
}

// ---------------- k_main: 4 phases, 3 tree barriers ----------------
__global__ void __launch_bounds__(NT, 4)
k_main(const int* __restrict__ attr_row, const int* __restrict__ attr_col,
       const int* __restrict__ edge, const int* __restrict__ jmsk,
       const int* __restrict__ jaug, const float* __restrict__ w2,
       const float* __restrict__ bias2, float* __restrict__ out,
       char* __restrict__ ws) {
    __shared__ __align__(16) char smem[4640];
    unsigned* ebt  = (unsigned*)(ws + OFF_EBT);
    unsigned* jmt  = (unsigned*)(ws + OFF_JMT);
    unsigned* jat  = (unsigned*)(ws + OFF_JAT);
    unsigned* cnt  = (unsigned*)(ws + OFF_CNT);
    unsigned* bar  = (unsigned*)(ws + OFF_BAR);
    float*    dinv = (float*)(ws + OFF_DINV);
    int*      deg  = (int*)(ws + OFF_DEG);
    unsigned* ccol = (unsigned*)(ws + OFF_CCOL);
    int*      adj  = (int*)(ws + OFF_ADJ);
    float*    w1t  = (float*)(ws + OFF_W1T);
    float*    h1s  = (float*)(ws + OFF_H1);
    float*    h2s  = (float*)(ws + OFF_H2);

    const int b = blockIdx.x, t = threadIdx.x;
    const int gid = b * NT + t;

    // ---- P1: four independent scatters (ebitT | jmT | jaT | attr slots)
    {
        for (int i = gid; i < E_ + NNZ_JM + NNZ_JA + NNZ_ATTR; i += GSIZE) {
            if (i < E_) {
                int p = edge[i], q = edge[E_ + i];
                atomicOr(&ebt[(size_t)q * WORDS + (p >> 5)], 1u << (p & 31));
            } else if (i < E_ + NNZ_JM) {
                int j = i - E_;
                int p = jmsk[j], q = jmsk[NNZ_JM + j];
                atomicOr(&jmt[(size_t)q * WORDS + (p >> 5)], 1u << (p & 31));
            } else if (i < E_ + NNZ_JM + NNZ_JA) {
                int j = i - E_ - NNZ_JM;
                int p = jaug[j], q = jaug[NNZ_JA + j];
                atomicOr(&jat[(size_t)q * WORDS + (p >> 5)], 1u << (p & 31));
            } else {
                int j = i - E_ - NNZ_JM - NNZ_JA;
                int r = attr_row[j];
                unsigned pos = atomicAdd(&cnt[r], 1u);
                if (pos < ASTR) ccol[(size_t)r * ASTR + pos] = (unsigned)attr_col[j];
            }
        }
    }
    gridbar(bar, 1u);

    // ---- P2: per-row (4 rows/block, 1 row/wave): w = (e&jm)|ja|diag on the fly,
    //          popcount -> dinv/deg, extract adj; then h1s for the SAME 4 rows.
    {
        unsigned* cols = (unsigned*)smem;            // 128 u32
        float* part = (float*)(smem + 512);          // [4][64][4] f32
        float* sdinv = (float*)(smem + 512 + 4096);  // 4 f32
        int wv = t >> 6, lane = t & 63;
        int q = 4 * b + wv;
        {
            const uint2* er = (const uint2*)(ebt + (size_t)q * WORDS);
            const uint2* jr = (const uint2*)(jmt + (size_t)q * WORDS);
            const uint2* ar = (const uint2*)(jat + (size_t)q * WORDS);
            uint2 e2 = er[lane], j2 = jr[lane], a2 = ar[lane];
            unsigned w0 = (e2.x & j2.x) | a2.x;
            unsigned w1b = (e2.y & j2.y) | a2.y;
            int dw = q >> 5;
            if ((dw >> 1) == lane) {
                if (dw & 1) w1b |= 1u << (q & 31); else w0 |= 1u << (q & 31);
            }
            int c = __popc(w0) + __popc(w1b);
            int pre = c;
            #pragma unroll
            for (int d2 = 1; d2 < 64; d2 <<= 1) {
                int x = __shfl_up(pre, d2);
                if (lane >= d2) pre += x;
            }
            int excl = pre - c;
            int total = __shfl(pre, 63);
            if (lane == 0) {
                float dv = rsqrtf((float)total);
                dinv[q] = dv;
                sdinv[wv] = dv;
                deg[q] = total < ADJ_STRIDE ? total : ADJ_STRIDE;
            }
            unsigned idx = (unsigned)excl;
            int* arow = adj + (size_t)q * ADJ_STRIDE;
            int base0 = lane * 64;
            while (w0)  { int bp = __ffs(w0) - 1;  w0  &= w0 - 1;  if (idx < ADJ_STRIDE) arow[idx] = base0 + bp;      ++idx; }
            while (w1b) { int bp = __ffs(w1b) - 1; w1b &= w1b - 1; if (idx < ADJ_STRIDE) arow[idx] = base0 + 32 + bp; ++idx; }
        }
        __syncthreads();
        int g = t >> 6;
        for (int i = 0; i < 4; ++i) {
            int r = 4 * b + i;
            unsigned m = min(cnt[r], (unsigned)ASTR);
            if ((unsigned)t < m) cols[t] = ccol[(size_t)r * ASTR + t];
            __syncthreads();
            float4 acc = make_float4(0.f, 0.f, 0.f, 0.f);
            unsigned j = (unsigned)g;
            for (; j + 12 < m; j += 16) {
                unsigned c0 = cols[j], c1 = cols[j + 4], c2 = cols[j + 8], c3 = cols[j + 12];
                float4 v0 = *(const float4*)&w1t[(size_t)c0 * H_ + lane * 4];
                float4 v1 = *(const float4*)&w1t[(size_t)c1 * H_ + lane * 4];
                float4 v2 = *(const float4*)&w1t[(size_t)c2 * H_ + lane * 4];
                float4 v3 = *(const float4*)&w1t[(size_t)c3 * H_ + lane * 4];
                acc.x += v0.x + v1.x + v2.x + v3.x;
                acc.y += v0.y + v1.y + v2.y + v3.y;
                acc.z += v0.z + v1.z + v2.z + v3.z;
                acc.w += v0.w + v1.w + v2.w + v3.w;
            }
            for (; j < m; j += 4) {
                unsigned c0 = cols[j];
                float4 v0 = *(const float4*)&w1t[(size_t)c0 * H_ + lane * 4];
                acc.x += v0.x; acc.y += v0.y; acc.z += v0.z; acc.w += v0.w;
            }
            ((float4*)part)[g * 64 + lane] = acc;
            __syncthreads();
            int comp = t & 3, idx4 = t >> 2;
            float s0 = part[(0 * 64 + idx4) * 4 + comp];
            float s1 = part[(1 * 64 + idx4) * 4 + comp];
            float s2 = part[(2 * 64 + idx4) * 4 + comp];
            float s3 = part[(3 * 64 + idx4) * 4 + comp];
            h1s[(size_t)r * H_ + t] = (s0 + s1 + s2 + s3) * sdinv[i];
            __syncthreads();
        }
    }
    gridbar(bar, 2u);

    // ---- P3: out1 = relu(dinv[q]*sum_adj h1s); h2s = dinv[q]*(out1 @ W2^T)
    {
        int* adj_s = (int*)smem;                        // 128 i32
        float* hrow = (float*)(smem + 512);             // 256 f32
        float* partial = (float*)(smem + 512 + 1024);   // [16][17] f32
        int c = t & 15, g = t >> 4;
        float w2r[16];
        #pragma unroll
        for (int kk = 0; kk < 16; ++kk) w2r[kk] = w2[(size_t)c * H_ + g * 16 + kk];
        for (int i = 0; i < 4; ++i) {
            int q = 4 * b + i;
            __syncthreads();
            if (t < ADJ_STRIDE) adj_s[t] = adj[(size_t)q * ADJ_STRIDE + t];
            __syncthreads();
            int dg = deg[q];
            float acc = 0.f;
            int j = 0;
            for (; j + 4 <= dg; j += 4) {
                int p0 = adj_s[j], p1 = adj_s[j + 1], p2 = adj_s[j + 2], p3 = adj_s[j + 3];
                acc += h1s[(size_t)p0 * H_ + t] + h1s[(size_t)p1 * H_ + t]
                     + h1s[(size_t)p2 * H_ + t] + h1s[(size_t)p3 * H_ + t];
            }
            for (; j < dg; ++j) acc += h1s[(size_t)adj_s[j] * H_ + t];
            float dq = dinv[q];
            hrow[t] = fmaxf(acc * dq, 0.f);
            __syncthreads();
            float part = 0.f;
            #pragma unroll
            for (int kk = 0; kk < 16; ++kk) part += hrow[g * 16 + kk] * w2r[kk];
            partial[g * 17 + c] = part;
            __syncthreads();
            if (t < 16) {
                float s = 0.f;
                #pragma unroll
                for (int g2 = 0; g2 < 16; ++g2) s += partial[g2 * 17 + t];
                h2s[(size_t)q * C_ + t] = s * dq;
            }
        }
    }
    gridbar(bar, 3u);

    // ---- P4: out[q,c] = dinv[q] * sum_adj h2s[p,c] + bias[c]  (1 row/wave)
    {
        int wv = t >> 6, lane = t & 63;
        int q = 4 * b + wv;
        int c = lane & 15, prt = lane >> 4;
        int dg = deg[q];
        const int* arow = adj + (size_t)q * ADJ_STRIDE;
        float acc = 0.f;
        for (int j = prt; j < dg; j += 4)
            acc += h2s[(size_t)arow[j] * C_ + c];
        acc += __shfl_down(acc, 32);
        acc += __shfl_down(acc, 16);
        if (lane < 16)
            out[(size_t)q * C_ + c] = dinv[q] * acc + bias2[c];
    }
}

// ---------------- launch ----------------

extern "C" void kernel_launch(void* const* d_in, const int* in_sizes, int n_in,
                              void* d_out, int out_size, void* d_ws, size_t ws_size,
                              hipStream_t stream) {
    const int*   attr_row = (const int*)d_in[0];
    const int*   attr_col = (const int*)d_in[1];
    const int*   edge     = (const int*)d_in[2];   // [2][E_]
    const int*   jmsk     = (const int*)d_in[3];   // [2][NNZ_JM]
    const int*   jaug     = (const int*)d_in[4];   // [2][NNZ_JA]
    const float* w1       = (const float*)d_in[5]; // [H_][D_]
    const float* w2       = (const float*)d_in[6]; // [C_][H_]
    const float* bias2    = (const float*)d_in[7]; // [C_]
    float*       out      = (float*)d_out;

    char*  ws  = (char*)d_ws;
    float* w1t = (float*)(ws + OFF_W1T);

    k_pre<<<ZB_BLOCKS + TR_BLOCKS, NT, 0, stream>>>(w1, w1t, (uint4*)d_ws);
    k_main<<<NB, NT, 0, stream>>>(attr_row, attr_col, edge, jmsk, jaug,
                                  w2, bias2, out, ws);
}

// Round 7
// 92.461 us; speedup vs baseline: 10.1822x; 2.3152x over previous
//
#include <hip/hip_runtime.h>

#define N_      4096
#define D_      4096
#define H_      256
#define C_      16
#define NNZ_ATTR 262144
#define E_      131072
#define NNZ_JM  400000
#define NNZ_JA  80000
#define WORDS   128        // N_/32 words per bitmask row
#define ADJ_STRIDE 128     // max neighbors kept per row (col-deg ~21 avg, max ~45)
#define ASTR    128        // attr cols per row cap (mean 64, 8 sigma)
#define NT      256

// ---------------- workspace layout (bytes), ~18.3 MB ----------------
#define OFF_EBT  ((size_t)0)                        // 2 MB  edge bitmask transposed [q][p]
#define OFF_JMT  ((size_t)(2u<<20))                 // 2 MB  jm bitmask transposed
#define OFF_JAT  ((size_t)(4u<<20))                 // 2 MB  ja bitmask transposed
#define OFF_CNT  ((size_t)(6u<<20))                 // 16 KB attr row counts
#define OFF_DINV (OFF_CNT + (size_t)(16u<<10))      // 16 KB dinv
#define OFF_DEG  (OFF_CNT + (size_t)(32u<<10))      // 16 KB adj degree
#define OFF_CCOL (OFF_CNT + (size_t)(48u<<10))      // 2 MB  attr col slots [N][ASTR]
#define OFF_ADJ  (OFF_CCOL + (size_t)(2u<<20))      // 2 MB  adjacency lists [N][128]
#define OFF_W1T  (OFF_ADJ + (size_t)(2u<<20))       // 4 MB  W1 transposed [D][H]
#define OFF_H1   (OFF_W1T + (size_t)(4u<<20))       // 4 MB  h1s = dinv[r]*h1[r]
#define OFF_H2   (OFF_H1  + (size_t)(4u<<20))       // 256 KB h2s

#define ZERO_BYTES (OFF_CNT + (size_t)(16u<<10))    // ebt+jmt+jat+cnt = 6307840
#define ZB_BLOCKS  1540                             // ZERO_BYTES/16/256 exactly
#define TR_BLOCKS  1024
#define SC_ITEMS   (E_ + NNZ_JM + NNZ_JA + NNZ_ATTR)  // 873216
#define SC_BLOCKS  (SC_ITEMS / NT)                  // 3411 exactly

// ---------------- K1: zero masks/cnt + transpose W1 ----------------
__global__ void k_pre(const float* __restrict__ w1, float* __restrict__ w1t,
                      uint4* __restrict__ zp) {
    __shared__ float tile[32][33];
    int b = blockIdx.x, t = threadIdx.x;
    if (b < ZB_BLOCKS) {
        zp[(size_t)b * NT + t] = make_uint4(0u, 0u, 0u, 0u);
    } else {
        int bb = b - ZB_BLOCKS;
        int gx = bb & 127, gy = bb >> 7;             // 128 D-tiles, 8 H-tiles
        int tx = t & 31, ty = t >> 5;                // (32,8)
        int col = gx * 32 + tx;
        #pragma unroll
        for (int j = 0; j < 4; ++j)
            tile[ty + j * 8][tx] = w1[(size_t)(gy * 32 + ty + j * 8) * D_ + col];
        __syncthreads();
        int ocol = gy * 32 + tx;
        #pragma unroll
        for (int j = 0; j < 4; ++j)
            w1t[(size_t)(gx * 32 + ty + j * 8) * H_ + ocol] = tile[tx][ty + j * 8];
    }
}

// ---------------- K2: four independent scatters, 1 item/thread ----------------
__global__ void k_scatter(const int* __restrict__ attr_row, const int* __restrict__ attr_col,
                          const int* __restrict__ edge, const int* __restrict__ jmsk,
                          const int* __restrict__ jaug,
                          unsigned* __restrict__ ebt, unsigned* __restrict__ jmt,
                          unsigned* __restrict__ jat, unsigned* __restrict__ cnt,
                          unsigned* __restrict__ ccol) {
    int i = blockIdx.x * NT + threadIdx.x;
    if (i < E_) {
        int p = edge[i], q = edge[E_ + i];
        atomicOr(&ebt[(size_t)q * WORDS + (p >> 5)], 1u << (p & 31));
    } else if (i < E_ + NNZ_JM) {
        int j = i - E_;
        int p = jmsk[j], q = jmsk[NNZ_JM + j];
        atomicOr(&jmt[(size_t)q * WORDS + (p >> 5)], 1u << (p & 31));
    } else if (i < E_ + NNZ_JM + NNZ_JA) {
        int j = i - E_ - NNZ_JM;
        int p = jaug[j], q = jaug[NNZ_JA + j];
        atomicOr(&jat[(size_t)q * WORDS + (p >> 5)], 1u << (p & 31));
    } else {
        int j = i - E_ - NNZ_JM - NNZ_JA;
        int r = attr_row[j];
        unsigned pos = atomicAdd(&cnt[r], 1u);
        if (pos < ASTR) ccol[(size_t)r * ASTR + pos] = (unsigned)attr_col[j];
    }
}

// ---------------- K3: per-row mask combine -> adj/dinv/deg, then h1s ----------------
// 1024 blocks x 256; 4 rows/block (1 row/wave for extraction, all waves for h1s)
__global__ void k_rowh1(const unsigned* __restrict__ ebt, const unsigned* __restrict__ jmt,
                        const unsigned* __restrict__ jat, const unsigned* __restrict__ cnt,
                        const unsigned* __restrict__ ccol, const float* __restrict__ w1t,
                        float* __restrict__ dinv, int* __restrict__ deg,
                        int* __restrict__ adj, float* __restrict__ h1s) {
    __shared__ __align__(16) char smem[4640];
    unsigned* cols = (unsigned*)smem;            // 128 u32 (512 B)
    float* part = (float*)(smem + 512);          // [4][64][4] f32 (4096 B)
    float* sdinv = (float*)(smem + 512 + 4096);  // 4 f32
    const int b = blockIdx.x, t = threadIdx.x;
    int wv = t >> 6, lane = t & 63;
    int q = 4 * b + wv;
    {
        const uint2* er = (const uint2*)(ebt + (size_t)q * WORDS);
        const uint2* jr = (const uint2*)(jmt + (size_t)q * WORDS);
        const uint2* ar = (const uint2*)(jat + (size_t)q * WORDS);
        uint2 e2 = er[lane], j2 = jr[lane], a2 = ar[lane];
        unsigned w0 = (e2.x & j2.x) | a2.x;
        unsigned w1b = (e2.y & j2.y) | a2.y;
        int dw = q >> 5;
        if ((dw >> 1) == lane) {
            if (dw & 1) w1b |= 1u << (q & 31); else w0 |= 1u << (q & 31);
        }
        int c = __popc(w0) + __popc(w1b);
        int pre = c;
        #pragma unroll
        for (int d2 = 1; d2 < 64; d2 <<= 1) {
            int x = __shfl_up(pre, d2);
            if (lane >= d2) pre += x;
        }
        int excl = pre - c;
        int total = __shfl(pre, 63);
        if (lane == 0) {
            float dv = rsqrtf((float)total);
            dinv[q] = dv;
            sdinv[wv] = dv;
            deg[q] = total < ADJ_STRIDE ? total : ADJ_STRIDE;
        }
        unsigned idx = (unsigned)excl;
        int* arow = adj + (size_t)q * ADJ_STRIDE;
        int base0 = lane * 64;
        while (w0)  { int bp = __ffs(w0) - 1;  w0  &= w0 - 1;  if (idx < ADJ_STRIDE) arow[idx] = base0 + bp;      ++idx; }
        while (w1b) { int bp = __ffs(w1b) - 1; w1b &= w1b - 1; if (idx < ADJ_STRIDE) arow[idx] = base0 + 32 + bp; ++idx; }
    }
    __syncthreads();
    int g = t >> 6;
    for (int i = 0; i < 4; ++i) {
        int r = 4 * b + i;
        unsigned m = min(cnt[r], (unsigned)ASTR);
        if ((unsigned)t < m) cols[t] = ccol[(size_t)r * ASTR + t];
        __syncthreads();
        float4 acc = make_float4(0.f, 0.f, 0.f, 0.f);
        unsigned j = (unsigned)g;
        for (; j + 12 < m; j += 16) {
            unsigned c0 = cols[j], c1 = cols[j + 4], c2 = cols[j + 8], c3 = cols[j + 12];
            float4 v0 = *(const float4*)&w1t[(size_t)c0 * H_ + lane * 4];
            float4 v1 = *(const float4*)&w1t[(size_t)c1 * H_ + lane * 4];
            float4 v2 = *(const float4*)&w1t[(size_t)c2 * H_ + lane * 4];
            float4 v3 = *(const float4*)&w1t[(size_t)c3 * H_ + lane * 4];
            acc.x += v0.x + v1.x + v2.x + v3.x;
            acc.y += v0.y + v1.y + v2.y + v3.y;
            acc.z += v0.z + v1.z + v2.z + v3.z;
            acc.w += v0.w + v1.w + v2.w + v3.w;
        }
        for (; j < m; j += 4) {
            unsigned c0 = cols[j];
            float4 v0 = *(const float4*)&w1t[(size_t)c0 * H_ + lane * 4];
            acc.x += v0.x; acc.y += v0.y; acc.z += v0.z; acc.w += v0.w;
        }
        ((float4*)part)[g * 64 + lane] = acc;
        __syncthreads();
        int comp = t & 3, idx4 = t >> 2;
        float s0 = part[(0 * 64 + idx4) * 4 + comp];
        float s1 = part[(1 * 64 + idx4) * 4 + comp];
        float s2 = part[(2 * 64 + idx4) * 4 + comp];
        float s3 = part[(3 * 64 + idx4) * 4 + comp];
        h1s[(size_t)r * H_ + t] = (s0 + s1 + s2 + s3) * sdinv[i];
        __syncthreads();
    }
}

// ---------------- K4: out1 = relu(dinv*sum_adj h1s); h2s = dinv*(out1 @ W2^T) ----------------
__global__ void k_prop1(const int* __restrict__ adj, const int* __restrict__ deg,
                        const float* __restrict__ dinv, const float* __restrict__ h1s,
                        const float* __restrict__ w2, float* __restrict__ h2s) {
    __shared__ __align__(16) char smem[2688];
    int* adj_s = (int*)smem;                        // 128 i32
    float* hrow = (float*)(smem + 512);             // 256 f32
    float* partial = (float*)(smem + 512 + 1024);   // [16][17] f32
    const int b = blockIdx.x, t = threadIdx.x;
    int c = t & 15, g = t >> 4;
    float w2r[16];
    #pragma unroll
    for (int kk = 0; kk < 16; ++kk) w2r[kk] = w2[(size_t)c * H_ + g * 16 + kk];
    for (int i = 0; i < 4; ++i) {
        int q = 4 * b + i;
        __syncthreads();
        if (t < ADJ_STRIDE) adj_s[t] = adj[(size_t)q * ADJ_STRIDE + t];
        __syncthreads();
        int dg = deg[q];
        float acc = 0.f;
        int j = 0;
        for (; j + 4 <= dg; j += 4) {
            int p0 = adj_s[j], p1 = adj_s[j + 1], p2 = adj_s[j + 2], p3 = adj_s[j + 3];
            acc += h1s[(size_t)p0 * H_ + t] + h1s[(size_t)p1 * H_ + t]
                 + h1s[(size_t)p2 * H_ + t] + h1s[(size_t)p3 * H_ + t];
        }
        for (; j < dg; ++j) acc += h1s[(size_t)adj_s[j] * H_ + t];
        float dq = dinv[q];
        hrow[t] = fmaxf(acc * dq, 0.f);
        __syncthreads();
        float part = 0.f;
        #pragma unroll
        for (int kk = 0; kk < 16; ++kk) part += hrow[g * 16 + kk] * w2r[kk];
        partial[g * 17 + c] = part;
        __syncthreads();
        if (t < 16) {
            float s = 0.f;
            #pragma unroll
            for (int g2 = 0; g2 < 16; ++g2) s += partial[g2 * 17 + t];
            h2s[(size_t)q * C_ + t] = s * dq;
        }
    }
}

// ---------------- K5: out[q,c] = dinv[q]*sum_adj h2s[p,c] + bias[c] ----------------
__global__ void k_prop2(const int* __restrict__ adj, const int* __restrict__ deg,
                        const float* __restrict__ dinv, const float* __restrict__ h2s,
                        const float* __restrict__ bias, float* __restrict__ out) {
    const int b = blockIdx.x, t = threadIdx.x;
    int wv = t >> 6, lane = t & 63;
    int q = 4 * b + wv;
    int c = lane & 15, prt = lane >> 4;
    int dg = deg[q];
    const int* arow = adj + (size_t)q * ADJ_STRIDE;
    float acc = 0.f;
    for (int j = prt; j < dg; j += 4)
        acc += h2s[(size_t)arow[j] * C_ + c];
    acc += __shfl_down(acc, 32);
    acc += __shfl_down(acc, 16);
    if (lane < 16)
        out[(size_t)q * C_ + c] = dinv[q] * acc + bias[c];
}

// ---------------- launch ----------------

extern "C" void kernel_launch(void* const* d_in, const int* in_sizes, int n_in,
                              void* d_out, int out_size, void* d_ws, size_t ws_size,
                              hipStream_t stream) {
    const int*   attr_row = (const int*)d_in[0];
    const int*   attr_col = (const int*)d_in[1];
    const int*   edge     = (const int*)d_in[2];   // [2][E_]
    const int*   jmsk     = (const int*)d_in[3];   // [2][NNZ_JM]
    const int*   jaug     = (const int*)d_in[4];   // [2][NNZ_JA]
    const float* w1       = (const float*)d_in[5]; // [H_][D_]
    const float* w2       = (const float*)d_in[6]; // [C_][H_]
    const float* bias2    = (const float*)d_in[7]; // [C_]
    float*       out      = (float*)d_out;

    char* ws = (char*)d_ws;
    unsigned* ebt  = (unsigned*)(ws + OFF_EBT);
    unsigned* jmt  = (unsigned*)(ws + OFF_JMT);
    unsigned* jat  = (unsigned*)(ws + OFF_JAT);
    unsigned* cnt  = (unsigned*)(ws + OFF_CNT);
    float*    dinv = (float*)(ws + OFF_DINV);
    int*      deg  = (int*)(ws + OFF_DEG);
    unsigned* ccol = (unsigned*)(ws + OFF_CCOL);
    int*      adj  = (int*)(ws + OFF_ADJ);
    float*    w1t  = (float*)(ws + OFF_W1T);
    float*    h1s  = (float*)(ws + OFF_H1);
    float*    h2s  = (float*)(ws + OFF_H2);

    k_pre<<<ZB_BLOCKS + TR_BLOCKS, NT, 0, stream>>>(w1, w1t, (uint4*)d_ws);
    k_scatter<<<SC_BLOCKS, NT, 0, stream>>>(attr_row, attr_col, edge, jmsk, jaug,
                                            ebt, jmt, jat, cnt, ccol);
    k_rowh1<<<N_ / 4, NT, 0, stream>>>(ebt, jmt, jat, cnt, ccol, w1t,
                                       dinv, deg, adj, h1s);
    k_prop1<<<N_ / 4, NT, 0, stream>>>(adj, deg, dinv, h1s, w2, h2s);
    k_prop2<<<N_ / 4, NT, 0, stream>>>(adj, deg, dinv, h2s, bias2, out);
}

// Round 8
// 81.515 us; speedup vs baseline: 11.5496x; 1.1343x over previous
//
#include <hip/hip_runtime.h>

#define N_      4096
#define D_      4096
#define H_      256
#define C_      16
#define NNZ_ATTR 262144
#define E_      131072
#define NNZ_JM  400000
#define NNZ_JA  80000
#define WORDS   128        // N_/32 words per bitmask row
#define ADJ_STRIDE 128     // max neighbors kept per row (deg ~21 avg, max ~45)
#define ASTR    128        // attr cols per row cap (mean 64, 8 sigma)
#define NT      256

// ---------------- workspace layout (bytes), ~16.3 MB ----------------
#define OFF_EBT  ((size_t)0)                        // 2 MB  edge bitmask transposed [q][p]
#define OFF_ABT  ((size_t)(2u<<20))                 // 2 MB  a_aug^T bitmask [q][p]
#define OFF_CNT  ((size_t)(4u<<20))                 // 16 KB attr row counts
#define OFF_DINV (OFF_CNT + (size_t)(16u<<10))      // 16 KB dinv
#define OFF_DEG  (OFF_CNT + (size_t)(32u<<10))      // 16 KB adj degree
#define OFF_CCOL (OFF_CNT + (size_t)(48u<<10))      // 2 MB  attr col slots [N][ASTR]
#define OFF_ADJ  (OFF_CCOL + (size_t)(2u<<20))      // 2 MB  adjacency lists [N][128]
#define OFF_W1T  (OFF_ADJ + (size_t)(2u<<20))       // 4 MB  W1 transposed [D][H]
#define OFF_H1   (OFF_W1T + (size_t)(4u<<20))       // 4 MB  h1s = dinv[r]*h1[r]
#define OFF_H2   (OFF_H1  + (size_t)(4u<<20))       // 256 KB h2s

#define ZERO_BYTES (OFF_CNT + (size_t)(16u<<10))    // ebt+abt+cnt = 4MB+16KB
#define ZB_BLOCKS  1028                             // ZERO_BYTES/16/256 exactly

// k_scat1 block ranges (each range branch-uniform per block)
#define SB_ATTR  0                                  // 1024 blocks (exact)
#define SB_EDGE  1024                               // 512 blocks (exact)
#define SB_JA    1536                               // 313 blocks (guarded)
#define SB_DIAG  1849                               // 16 blocks (exact)
#define SB_TR    1865                               // 1024 transpose blocks
#define SB_TOTAL 2889

// ---------------- K1: zero ebt/abt/cnt ----------------
__global__ void k_zero(uint4* __restrict__ zp) {
    zp[(size_t)blockIdx.x * NT + threadIdx.x] = make_uint4(0u, 0u, 0u, 0u);
}

// ---------------- K2: attr scatter | edge bitmask | ja->abt | diag->abt | W1^T ----------------
__global__ void k_scat1(const int* __restrict__ attr_row, const int* __restrict__ attr_col,
                        const int* __restrict__ edge, const int* __restrict__ jaug,
                        const float* __restrict__ w1,
                        unsigned* __restrict__ ebt, unsigned* __restrict__ abt,
                        unsigned* __restrict__ cnt, unsigned* __restrict__ ccol,
                        float* __restrict__ w1t) {
    __shared__ float tile[32][33];
    const int b = blockIdx.x, t = threadIdx.x;
    if (b < SB_EDGE) {                       // attr: 262144 items exact
        int i = b * NT + t;
        int r = attr_row[i];
        unsigned pos = atomicAdd(&cnt[r], 1u);
        if (pos < ASTR) ccol[(size_t)r * ASTR + pos] = (unsigned)attr_col[i];
    } else if (b < SB_JA) {                  // edges -> ebt: 131072 exact
        int j = (b - SB_EDGE) * NT + t;
        int p = edge[j], q = edge[E_ + j];
        atomicOr(&ebt[(size_t)q * WORDS + (p >> 5)], 1u << (p & 31));
    } else if (b < SB_DIAG) {                // ja -> abt: 80000 guarded
        int j = (b - SB_JA) * NT + t;
        if (j < NNZ_JA) {
            int p = jaug[j], q = jaug[NNZ_JA + j];
            atomicOr(&abt[(size_t)q * WORDS + (p >> 5)], 1u << (p & 31));
        }
    } else if (b < SB_TR) {                  // diag -> abt: 4096 exact
        int r = (b - SB_DIAG) * NT + t;
        atomicOr(&abt[(size_t)r * WORDS + (r >> 5)], 1u << (r & 31));
    } else {                                 // W1 [H,D] -> W1T [D,H]
        int bb = b - SB_TR;
        int gx = bb & 127, gy = bb >> 7;     // 128 D-tiles, 8 H-tiles
        int tx = t & 31, ty = t >> 5;        // (32,8)
        int col = gx * 32 + tx;
        #pragma unroll
        for (int j = 0; j < 4; ++j)
            tile[ty + j * 8][tx] = w1[(size_t)(gy * 32 + ty + j * 8) * D_ + col];
        __syncthreads();
        int ocol = gy * 32 + tx;
        #pragma unroll
        for (int j = 0; j < 4; ++j)
            w1t[(size_t)(gx * 32 + ty + j * 8) * H_ + ocol] = tile[tx][ty + j * 8];
    }
}

// ---------------- K3: jm entries probe ebt; hits -> abt ----------------
__global__ void k_scat2(const int* __restrict__ jmsk,
                        const unsigned* __restrict__ ebt, unsigned* __restrict__ abt) {
    int i = blockIdx.x * NT + threadIdx.x;
    if (i >= NNZ_JM) return;
    int p = jmsk[i], q = jmsk[NNZ_JM + i];
    size_t w = (size_t)q * WORDS + (p >> 5);
    if ((ebt[w] >> (p & 31)) & 1u)
        atomicOr(&abt[w], 1u << (p & 31));
}

// ---------------- K4: abt row -> adj/dinv/deg, then h1s (4 rows/block) ----------------
__global__ void k_rowh1(const unsigned* __restrict__ abt, const unsigned* __restrict__ cnt,
                        const unsigned* __restrict__ ccol, const float* __restrict__ w1t,
                        float* __restrict__ dinv, int* __restrict__ deg,
                        int* __restrict__ adj, float* __restrict__ h1s) {
    __shared__ __align__(16) char smem[4640];
    unsigned* cols = (unsigned*)smem;            // 128 u32
    float* part = (float*)(smem + 512);          // [4][64][4] f32
    float* sdinv = (float*)(smem + 512 + 4096);  // 4 f32
    const int b = blockIdx.x, t = threadIdx.x;
    int wv = t >> 6, lane = t & 63;
    int q = 4 * b + wv;
    {
        uint2 m2 = ((const uint2*)(abt + (size_t)q * WORDS))[lane];
        unsigned w0 = m2.x, w1b = m2.y;
        int c = __popc(w0) + __popc(w1b);
        int pre = c;
        #pragma unroll
        for (int d2 = 1; d2 < 64; d2 <<= 1) {
            int x = __shfl_up(pre, d2);
            if (lane >= d2) pre += x;
        }
        int excl = pre - c;
        int total = __shfl(pre, 63);
        if (lane == 0) {
            float dv = rsqrtf((float)total);
            dinv[q] = dv;
            sdinv[wv] = dv;
            deg[q] = total < ADJ_STRIDE ? total : ADJ_STRIDE;
        }
        unsigned idx = (unsigned)excl;
        int* arow = adj + (size_t)q * ADJ_STRIDE;
        int base0 = lane * 64;
        while (w0)  { int bp = __ffs(w0) - 1;  w0  &= w0 - 1;  if (idx < ADJ_STRIDE) arow[idx] = base0 + bp;      ++idx; }
        while (w1b) { int bp = __ffs(w1b) - 1; w1b &= w1b - 1; if (idx < ADJ_STRIDE) arow[idx] = base0 + 32 + bp; ++idx; }
    }
    __syncthreads();
    int g = t >> 6;
    for (int i = 0; i < 4; ++i) {
        int r = 4 * b + i;
        unsigned m = min(cnt[r], (unsigned)ASTR);
        if ((unsigned)t < m) cols[t] = ccol[(size_t)r * ASTR + t];
        __syncthreads();
        float4 acc = make_float4(0.f, 0.f, 0.f, 0.f);
        unsigned j = (unsigned)g;
        for (; j + 12 < m; j += 16) {
            unsigned c0 = cols[j], c1 = cols[j + 4], c2 = cols[j + 8], c3 = cols[j + 12];
            float4 v0 = *(const float4*)&w1t[(size_t)c0 * H_ + lane * 4];
            float4 v1 = *(const float4*)&w1t[(size_t)c1 * H_ + lane * 4];
            float4 v2 = *(const float4*)&w1t[(size_t)c2 * H_ + lane * 4];
            float4 v3 = *(const float4*)&w1t[(size_t)c3 * H_ + lane * 4];
            acc.x += v0.x + v1.x + v2.x + v3.x;
            acc.y += v0.y + v1.y + v2.y + v3.y;
            acc.z += v0.z + v1.z + v2.z + v3.z;
            acc.w += v0.w + v1.w + v2.w + v3.w;
        }
        for (; j < m; j += 4) {
            unsigned c0 = cols[j];
            float4 v0 = *(const float4*)&w1t[(size_t)c0 * H_ + lane * 4];
            acc.x += v0.x; acc.y += v0.y; acc.z += v0.z; acc.w += v0.w;
        }
        ((float4*)part)[g * 64 + lane] = acc;
        __syncthreads();
        int comp = t & 3, idx4 = t >> 2;
        float s0 = part[(0 * 64 + idx4) * 4 + comp];
        float s1 = part[(1 * 64 + idx4) * 4 + comp];
        float s2 = part[(2 * 64 + idx4) * 4 + comp];
        float s3 = part[(3 * 64 + idx4) * 4 + comp];
        h1s[(size_t)r * H_ + t] = (s0 + s1 + s2 + s3) * sdinv[i];
        __syncthreads();
    }
}

// ---------------- K5: out1 = relu(dinv*sum_adj h1s); h2s = dinv*(out1 @ W2^T) ----------------
__global__ void k_prop1(const int* __restrict__ adj, const int* __restrict__ deg,
                        const float* __restrict__ dinv, const float* __restrict__ h1s,
                        const float* __restrict__ w2, float* __restrict__ h2s) {
    __shared__ __align__(16) char smem[2688];
    int* adj_s = (int*)smem;                        // 128 i32
    float* hrow = (float*)(smem + 512);             // 256 f32
    float* partial = (float*)(smem + 512 + 1024);   // [16][17] f32
    const int b = blockIdx.x, t = threadIdx.x;
    int c = t & 15, g = t >> 4;
    float w2r[16];
    #pragma unroll
    for (int kk = 0; kk < 16; ++kk) w2r[kk] = w2[(size_t)c * H_ + g * 16 + kk];
    for (int i = 0; i < 4; ++i) {
        int q = 4 * b + i;
        __syncthreads();
        if (t < ADJ_STRIDE) adj_s[t] = adj[(size_t)q * ADJ_STRIDE + t];
        __syncthreads();
        int dg = deg[q];
        float acc = 0.f;
        int j = 0;
        for (; j + 4 <= dg; j += 4) {
            int p0 = adj_s[j], p1 = adj_s[j + 1], p2 = adj_s[j + 2], p3 = adj_s[j + 3];
            acc += h1s[(size_t)p0 * H_ + t] + h1s[(size_t)p1 * H_ + t]
                 + h1s[(size_t)p2 * H_ + t] + h1s[(size_t)p3 * H_ + t];
        }
        for (; j < dg; ++j) acc += h1s[(size_t)adj_s[j] * H_ + t];
        float dq = dinv[q];
        hrow[t] = fmaxf(acc * dq, 0.f);
        __syncthreads();
        float part = 0.f;
        #pragma unroll
        for (int kk = 0; kk < 16; ++kk) part += hrow[g * 16 + kk] * w2r[kk];
        partial[g * 17 + c] = part;
        __syncthreads();
        if (t < 16) {
            float s = 0.f;
            #pragma unroll
            for (int g2 = 0; g2 < 16; ++g2) s += partial[g2 * 17 + t];
            h2s[(size_t)q * C_ + t] = s * dq;
        }
    }
}

// ---------------- K6: out[q,c] = dinv[q]*sum_adj h2s[p,c] + bias[c] ----------------
__global__ void k_prop2(const int* __restrict__ adj, const int* __restrict__ deg,
                        const float* __restrict__ dinv, const float* __restrict__ h2s,
                        const float* __restrict__ bias, float* __restrict__ out) {
    const int b = blockIdx.x, t = threadIdx.x;
    int wv = t >> 6, lane = t & 63;
    int q = 4 * b + wv;
    int c = lane & 15, prt = lane >> 4;
    int dg = deg[q];
    const int* arow = adj + (size_t)q * ADJ_STRIDE;
    float acc = 0.f;
    for (int j = prt; j < dg; j += 4)
        acc += h2s[(size_t)arow[j] * C_ + c];
    acc += __shfl_down(acc, 32);
    acc += __shfl_down(acc, 16);
    if (lane < 16)
        out[(size_t)q * C_ + c] = dinv[q] * acc + bias[c];
}

// ---------------- launch ----------------

extern "C" void kernel_launch(void* const* d_in, const int* in_sizes, int n_in,
                              void* d_out, int out_size, void* d_ws, size_t ws_size,
                              hipStream_t stream) {
    const int*   attr_row = (const int*)d_in[0];
    const int*   attr_col = (const int*)d_in[1];
    const int*   edge     = (const int*)d_in[2];   // [2][E_]
    const int*   jmsk     = (const int*)d_in[3];   // [2][NNZ_JM]
    const int*   jaug     = (const int*)d_in[4];   // [2][NNZ_JA]
    const float* w1       = (const float*)d_in[5]; // [H_][D_]
    const float* w2       = (const float*)d_in[6]; // [C_][H_]
    const float* bias2    = (const float*)d_in[7]; // [C_]
    float*       out      = (float*)d_out;

    char* ws = (char*)d_ws;
    unsigned* ebt  = (unsigned*)(ws + OFF_EBT);
    unsigned* abt  = (unsigned*)(ws + OFF_ABT);
    unsigned* cnt  = (unsigned*)(ws + OFF_CNT);
    float*    dinv = (float*)(ws + OFF_DINV);
    int*      deg  = (int*)(ws + OFF_DEG);
    unsigned* ccol = (unsigned*)(ws + OFF_CCOL);
    int*      adj  = (int*)(ws + OFF_ADJ);
    float*    w1t  = (float*)(ws + OFF_W1T);
    float*    h1s  = (float*)(ws + OFF_H1);
    float*    h2s  = (float*)(ws + OFF_H2);

    k_zero<<<ZB_BLOCKS, NT, 0, stream>>>((uint4*)d_ws);
    k_scat1<<<SB_TOTAL, NT, 0, stream>>>(attr_row, attr_col, edge, jaug, w1,
                                         ebt, abt, cnt, ccol, w1t);
    k_scat2<<<(NNZ_JM + NT - 1) / NT, NT, 0, stream>>>(jmsk, ebt, abt);
    k_rowh1<<<N_ / 4, NT, 0, stream>>>(abt, cnt, ccol, w1t, dinv, deg, adj, h1s);
    k_prop1<<<N_ / 4, NT, 0, stream>>>(adj, deg, dinv, h1s, w2, h2s);
    k_prop2<<<N_ / 4, NT, 0, stream>>>(adj, deg, dinv, h2s, bias2, out);
}

// Round 9
// 75.482 us; speedup vs baseline: 12.4726x; 1.0799x over previous
//
#include <hip/hip_runtime.h>

#define N_      4096
#define D_      4096
#define H_      256
#define C_      16
#define NNZ_ATTR 262144
#define E_      131072
#define NNZ_JM  400000
#define NNZ_JA  80000
#define WORDS   128        // N_/32 words per bitmask row
#define ADJ_STRIDE 128     // max neighbors kept per row (deg ~21 avg, max ~45)
#define ASTR    128        // attr cols per row cap (mean 64, 8 sigma)
#define NT      256

typedef _Float16 half8v __attribute__((ext_vector_type(8)));
typedef _Float16 half2v __attribute__((ext_vector_type(2)));

// ---------------- workspace layout (bytes), ~12.8 MB ----------------
#define OFF_EBT  ((size_t)0)                        // 2 MB  edge bitmask transposed [q][p]
#define OFF_ABT  ((size_t)(2u<<20))                 // 2 MB  a_aug^T bitmask [q][p]
#define OFF_CNT  ((size_t)(4u<<20))                 // 256 KB attr counts, 1 per 64B line
#define OFF_DINV (OFF_CNT + (size_t)(256u<<10))     // 16 KB dinv
#define OFF_DEG  (OFF_DINV + (size_t)(16u<<10))     // 16 KB adj degree
#define OFF_CCOL (OFF_DEG + (size_t)(16u<<10))      // 2 MB  attr col slots [N][ASTR]
#define OFF_ADJ  (OFF_CCOL + (size_t)(2u<<20))      // 2 MB  adjacency lists [N][128]
#define OFF_W1T  (OFF_ADJ + (size_t)(2u<<20))       // 2 MB  W1^T fp16 [D][H]
#define OFF_H1   (OFF_W1T + (size_t)(2u<<20))       // 2 MB  h1s fp16 [N][H]
#define OFF_H2   (OFF_H1  + (size_t)(2u<<20))       // 256 KB h2s f32

#define ZERO_BYTES ((size_t)((4u<<20)+(256u<<10)))  // ebt+abt+cnt = 4456448
#define ZB_BLOCKS  1088                             // ZERO_BYTES/16/256 exactly
#define TR_BLOCKS  1024

// k_scat1 block ranges
#define SB_EDGE  1024      // attr: blocks [0,1024)  (262144 exact)
#define SB_JA    1536      // edge: blocks [1024,1536) (131072 exact)
#define SB_DIAG  1849      // ja:   blocks [1536,1849) (80000 guarded)
#define SB_TOTAL 1865      // diag: blocks [1849,1865) (4096 exact)

// ---------------- K1: zero ebt/abt/cnt + W1 -> W1T fp16 ----------------
__global__ void k_pre(const float* __restrict__ w1, _Float16* __restrict__ w1t,
                      uint4* __restrict__ zp) {
    __shared__ float tile[32][33];
    int b = blockIdx.x, t = threadIdx.x;
    if (b < ZB_BLOCKS) {
        zp[(size_t)b * NT + t] = make_uint4(0u, 0u, 0u, 0u);
    } else {
        int bb = b - ZB_BLOCKS;
        int gx = bb & 127, gy = bb >> 7;     // 128 D-tiles, 8 H-tiles
        int tx = t & 31, ty = t >> 5;        // (32,8)
        int col = gx * 32 + tx;
        #pragma unroll
        for (int j = 0; j < 4; ++j)
            tile[ty + j * 8][tx] = w1[(size_t)(gy * 32 + ty + j * 8) * D_ + col];
        __syncthreads();
        int ocol = gy * 32 + tx;
        #pragma unroll
        for (int j = 0; j < 4; ++j)
            w1t[(size_t)(gx * 32 + ty + j * 8) * H_ + ocol] = (_Float16)tile[tx][ty + j * 8];
    }
}

// ---------------- K2: attr scatter | edge bitmask | ja->abt | diag->abt ----------------
__global__ void k_scat1(const int* __restrict__ attr_row, const int* __restrict__ attr_col,
                        const int* __restrict__ edge, const int* __restrict__ jaug,
                        unsigned* __restrict__ ebt, unsigned* __restrict__ abt,
                        unsigned* __restrict__ cnt, unsigned* __restrict__ ccol) {
    const int b = blockIdx.x, t = threadIdx.x;
    if (b < SB_EDGE) {                       // attr: 262144 exact
        int i = b * NT + t;
        int r = attr_row[i];
        unsigned pos = atomicAdd(&cnt[r << 4], 1u);   // padded: 1 counter / 64B line
        if (pos < ASTR) ccol[(size_t)r * ASTR + pos] = (unsigned)attr_col[i];
    } else if (b < SB_JA) {                  // edges -> ebt: 131072 exact
        int j = (b - SB_EDGE) * NT + t;
        int p = edge[j], q = edge[E_ + j];
        atomicOr(&ebt[(size_t)q * WORDS + (p >> 5)], 1u << (p & 31));
    } else if (b < SB_DIAG) {                // ja -> abt: 80000 guarded
        int j = (b - SB_JA) * NT + t;
        if (j < NNZ_JA) {
            int p = jaug[j], q = jaug[NNZ_JA + j];
            atomicOr(&abt[(size_t)q * WORDS + (p >> 5)], 1u << (p & 31));
        }
    } else {                                 // diag -> abt: 4096 exact
        int r = (b - SB_DIAG) * NT + t;
        atomicOr(&abt[(size_t)r * WORDS + (r >> 5)], 1u << (r & 31));
    }
}

// ---------------- K3: jm entries probe ebt; hits -> abt ----------------
__global__ void k_scat2(const int* __restrict__ jmsk,
                        const unsigned* __restrict__ ebt, unsigned* __restrict__ abt) {
    int i = blockIdx.x * NT + threadIdx.x;
    if (i >= NNZ_JM) return;
    int p = jmsk[i], q = jmsk[NNZ_JM + i];
    size_t w = (size_t)q * WORDS + (p >> 5);
    if ((ebt[w] >> (p & 31)) & 1u)
        atomicOr(&abt[w], 1u << (p & 31));
}

// ---------------- K4: abt row -> adj/dinv/deg, then h1s fp16 (4 rows/block) ----------------
__global__ void k_rowh1(const unsigned* __restrict__ abt, const unsigned* __restrict__ cnt,
                        const unsigned* __restrict__ ccol, const _Float16* __restrict__ w1t,
                        float* __restrict__ dinv, int* __restrict__ deg,
                        int* __restrict__ adj, _Float16* __restrict__ h1s) {
    __shared__ unsigned cols[128];
    __shared__ float part[4][2][32][8];   // 8 KB
    __shared__ float sdinv[4];
    const int b = blockIdx.x, t = threadIdx.x;
    int wv = t >> 6, lane = t & 63;
    int q = 4 * b + wv;
    {
        uint2 m2 = ((const uint2*)(abt + (size_t)q * WORDS))[lane];
        unsigned w0 = m2.x, w1b = m2.y;
        int c = __popc(w0) + __popc(w1b);
        int pre = c;
        #pragma unroll
        for (int d2 = 1; d2 < 64; d2 <<= 1) {
            int x = __shfl_up(pre, d2);
            if (lane >= d2) pre += x;
        }
        int excl = pre - c;
        int total = __shfl(pre, 63);
        if (lane == 0) {
            float dv = rsqrtf((float)total);
            dinv[q] = dv;
            sdinv[wv] = dv;
            deg[q] = total < ADJ_STRIDE ? total : ADJ_STRIDE;
        }
        unsigned idx = (unsigned)excl;
        int* arow = adj + (size_t)q * ADJ_STRIDE;
        int base0 = lane * 64;
        while (w0)  { int bp = __ffs(w0) - 1;  w0  &= w0 - 1;  if (idx < ADJ_STRIDE) arow[idx] = base0 + bp;      ++idx; }
        while (w1b) { int bp = __ffs(w1b) - 1; w1b &= w1b - 1; if (idx < ADJ_STRIDE) arow[idx] = base0 + 32 + bp; ++idx; }
    }
    __syncthreads();
    int g = t >> 6, hw = (t >> 5) & 1, l32 = t & 31;
    for (int i = 0; i < 4; ++i) {
        int r = 4 * b + i;
        int m = (int)min(cnt[r << 4], (unsigned)ASTR);
        if (t < m) cols[t] = ccol[(size_t)r * ASTR + t];
        __syncthreads();
        float acc[8];
        #pragma unroll
        for (int e = 0; e < 8; ++e) acc[e] = 0.f;
        int sub = (g << 1) + hw;             // 0..7: column slot within each 8-group
        for (int j = 0; j < m; j += 8) {
            int jc = j + sub;
            if (jc < m) {
                unsigned c = cols[jc];
                half8v v = *(const half8v*)(w1t + (size_t)c * H_ + l32 * 8);
                #pragma unroll
                for (int e = 0; e < 8; ++e) acc[e] += (float)v[e];
            }
        }
        #pragma unroll
        for (int e = 0; e < 8; ++e) part[g][hw][l32][e] = acc[e];
        __syncthreads();
        // thread t reduces H-element t over the 8 (g,hw) partials
        int l = t >> 3, e = t & 7;
        float s = 0.f;
        #pragma unroll
        for (int gg = 0; gg < 4; ++gg) {
            s += part[gg][0][l][e];
            s += part[gg][1][l][e];
        }
        h1s[(size_t)r * H_ + t] = (_Float16)(s * sdinv[i]);
        __syncthreads();
    }
}

// ---------------- K5: out1 = relu(dinv*sum_adj h1s); h2s = dinv*(out1 @ W2^T) ----------------
__global__ void k_prop1(const int* __restrict__ adj, const int* __restrict__ deg,
                        const float* __restrict__ dinv, const _Float16* __restrict__ h1s,
                        const float* __restrict__ w2, float* __restrict__ h2s) {
    __shared__ int adj_s[128];
    __shared__ float partial2[2][256];   // 2 KB
    __shared__ float hrow[256];
    __shared__ float partial[16][17];
    const int b = blockIdx.x, t = threadIdx.x;
    int g2 = t >> 7, tt = t & 127;       // half-block x 128 element-pairs
    int c = t & 15, gg = t >> 4;
    float w2r[16];
    #pragma unroll
    for (int kk = 0; kk < 16; ++kk) w2r[kk] = w2[(size_t)c * H_ + gg * 16 + kk];
    for (int i = 0; i < 4; ++i) {
        int q = 4 * b + i;
        __syncthreads();
        if (t < ADJ_STRIDE) adj_s[t] = adj[(size_t)q * ADJ_STRIDE + t];
        __syncthreads();
        int dg = deg[q];
        float ax = 0.f, ay = 0.f;
        int j = g2;
        for (; j + 2 < dg; j += 4) {
            int p0 = adj_s[j], p1 = adj_s[j + 2];
            half2v v0 = *(const half2v*)(h1s + (size_t)p0 * H_ + tt * 2);
            half2v v1 = *(const half2v*)(h1s + (size_t)p1 * H_ + tt * 2);
            ax += (float)v0[0] + (float)v1[0];
            ay += (float)v0[1] + (float)v1[1];
        }
        for (; j < dg; j += 2) {
            int p0 = adj_s[j];
            half2v v0 = *(const half2v*)(h1s + (size_t)p0 * H_ + tt * 2);
            ax += (float)v0[0];
            ay += (float)v0[1];
        }
        partial2[g2][2 * tt]     = ax;
        partial2[g2][2 * tt + 1] = ay;
        __syncthreads();
        float dq = dinv[q];
        hrow[t] = fmaxf((partial2[0][t] + partial2[1][t]) * dq, 0.f);
        __syncthreads();
        float p = 0.f;
        #pragma unroll
        for (int kk = 0; kk < 16; ++kk) p += hrow[gg * 16 + kk] * w2r[kk];
        partial[gg][c] = p;
        __syncthreads();
        if (t < 16) {
            float s = 0.f;
            #pragma unroll
            for (int g3 = 0; g3 < 16; ++g3) s += partial[g3][t];
            h2s[(size_t)q * C_ + t] = s * dq;
        }
    }
}

// ---------------- K6: out[q,c] = dinv[q]*sum_adj h2s[p,c] + bias[c] ----------------
__global__ void k_prop2(const int* __restrict__ adj, const int* __restrict__ deg,
                        const float* __restrict__ dinv, const float* __restrict__ h2s,
                        const float* __restrict__ bias, float* __restrict__ out) {
    const int b = blockIdx.x, t = threadIdx.x;
    int wv = t >> 6, lane = t & 63;
    int q = 4 * b + wv;
    int c = lane & 15, prt = lane >> 4;
    int dg = deg[q];
    const int* arow = adj + (size_t)q * ADJ_STRIDE;
    float acc = 0.f;
    for (int j = prt; j < dg; j += 4)
        acc += h2s[(size_t)arow[j] * C_ + c];
    acc += __shfl_down(acc, 32);
    acc += __shfl_down(acc, 16);
    if (lane < 16)
        out[(size_t)q * C_ + c] = dinv[q] * acc + bias[c];
}

// ---------------- launch ----------------

extern "C" void kernel_launch(void* const* d_in, const int* in_sizes, int n_in,
                              void* d_out, int out_size, void* d_ws, size_t ws_size,
                              hipStream_t stream) {
    const int*   attr_row = (const int*)d_in[0];
    const int*   attr_col = (const int*)d_in[1];
    const int*   edge     = (const int*)d_in[2];   // [2][E_]
    const int*   jmsk     = (const int*)d_in[3];   // [2][NNZ_JM]
    const int*   jaug     = (const int*)d_in[4];   // [2][NNZ_JA]
    const float* w1       = (const float*)d_in[5]; // [H_][D_]
    const float* w2       = (const float*)d_in[6]; // [C_][H_]
    const float* bias2    = (const float*)d_in[7]; // [C_]
    float*       out      = (float*)d_out;

    char* ws = (char*)d_ws;
    unsigned*  ebt  = (unsigned*)(ws + OFF_EBT);
    unsigned*  abt  = (unsigned*)(ws + OFF_ABT);
    unsigned*  cnt  = (unsigned*)(ws + OFF_CNT);
    float*     dinv = (float*)(ws + OFF_DINV);
    int*       deg  = (int*)(ws + OFF_DEG);
    unsigned*  ccol = (unsigned*)(ws + OFF_CCOL);
    int*       adj  = (int*)(ws + OFF_ADJ);
    _Float16*  w1t  = (_Float16*)(ws + OFF_W1T);
    _Float16*  h1s  = (_Float16*)(ws + OFF_H1);
    float*     h2s  = (float*)(ws + OFF_H2);

    k_pre<<<ZB_BLOCKS + TR_BLOCKS, NT, 0, stream>>>(w1, w1t, (uint4*)d_ws);
    k_scat1<<<SB_TOTAL, NT, 0, stream>>>(attr_row, attr_col, edge, jaug,
                                         ebt, abt, cnt, ccol);
    k_scat2<<<(NNZ_JM + NT - 1) / NT, NT, 0, stream>>>(jmsk, ebt, abt);
    k_rowh1<<<N_ / 4, NT, 0, stream>>>(abt, cnt, ccol, w1t, dinv, deg, adj, h1s);
    k_prop1<<<N_ / 4, NT, 0, stream>>>(adj, deg, dinv, h1s, w2, h2s);
    k_prop2<<<N_ / 4, NT, 0, stream>>>(adj, deg, dinv, h2s, bias2, out);
}

// Round 10
// 75.442 us; speedup vs baseline: 12.4792x; 1.0005x over previous
//
#include <hip/hip_runtime.h>

#define N_      4096
#define D_      4096
#define H_      256
#define C_      16
#define NNZ_ATTR 262144
#define E_      131072
#define NNZ_JM  400000
#define NNZ_JA  80000
#define WORDS   128        // N_/32 words per bitmask row
#define ADJ_STRIDE 128     // max neighbors kept per row (deg ~21 avg, max ~45)
#define ASTR    128        // attr cols per row cap (mean 64, 8 sigma)
#define NT      256

typedef _Float16 half8v __attribute__((ext_vector_type(8)));
typedef _Float16 half2v __attribute__((ext_vector_type(2)));

// ---------------- workspace layout (bytes), ~12.8 MB ----------------
#define OFF_EBT  ((size_t)0)                        // 2 MB  edge bitmask transposed [q][p]
#define OFF_ABT  ((size_t)(2u<<20))                 // 2 MB  a_aug^T bitmask [q][p]
#define OFF_CNT  ((size_t)(4u<<20))                 // 256 KB attr counts, 1 per 64B line
#define OFF_DINV (OFF_CNT + (size_t)(256u<<10))     // 16 KB dinv
#define OFF_DEG  (OFF_DINV + (size_t)(16u<<10))     // 16 KB adj degree
#define OFF_CCOL (OFF_DEG + (size_t)(16u<<10))      // 2 MB  attr col slots [N][ASTR]
#define OFF_ADJ  (OFF_CCOL + (size_t)(2u<<20))      // 2 MB  adjacency lists [N][128]
#define OFF_W1T  (OFF_ADJ + (size_t)(2u<<20))       // 2 MB  W1^T fp16 [D][H]
#define OFF_H1   (OFF_W1T + (size_t)(2u<<20))       // 2 MB  h1s fp16 [N][H]
#define OFF_H2   (OFF_H1  + (size_t)(2u<<20))       // 256 KB h2s f32

#define ZERO_BYTES ((size_t)((4u<<20)+(256u<<10)))  // ebt+abt+cnt = 4456448
#define ZB_BLOCKS  1088                             // ZERO_BYTES/16/256 exactly
#define TR_BLOCKS  1024

// k_scat1 block ranges
#define SB_EDGE  1024      // attr: blocks [0,1024)  (262144 exact)
#define SB_JA    1536      // edge: blocks [1024,1536) (131072 exact)
#define SB_DIAG  1849      // ja:   blocks [1536,1849) (80000 guarded)
#define SB_TOTAL 1865      // diag: blocks [1849,1865) (4096 exact)

// ---------------- K1: zero ebt/abt/cnt + W1 -> W1T fp16 ----------------
__global__ void k_pre(const float* __restrict__ w1, _Float16* __restrict__ w1t,
                      uint4* __restrict__ zp) {
    __shared__ float tile[32][33];
    int b = blockIdx.x, t = threadIdx.x;
    if (b < ZB_BLOCKS) {
        zp[(size_t)b * NT + t] = make_uint4(0u, 0u, 0u, 0u);
    } else {
        int bb = b - ZB_BLOCKS;
        int gx = bb & 127, gy = bb >> 7;     // 128 D-tiles, 8 H-tiles
        int tx = t & 31, ty = t >> 5;        // (32,8)
        int col = gx * 32 + tx;
        #pragma unroll
        for (int j = 0; j < 4; ++j)
            tile[ty + j * 8][tx] = w1[(size_t)(gy * 32 + ty + j * 8) * D_ + col];
        __syncthreads();
        int ocol = gy * 32 + tx;
        #pragma unroll
        for (int j = 0; j < 4; ++j)
            w1t[(size_t)(gx * 32 + ty + j * 8) * H_ + ocol] = (_Float16)tile[tx][ty + j * 8];
    }
}

// ---------------- K2: attr scatter | edge bitmask | ja->abt | diag->abt ----------------
__global__ void k_scat1(const int* __restrict__ attr_row, const int* __restrict__ attr_col,
                        const int* __restrict__ edge, const int* __restrict__ jaug,
                        unsigned* __restrict__ ebt, unsigned* __restrict__ abt,
                        unsigned* __restrict__ cnt, unsigned* __restrict__ ccol) {
    const int b = blockIdx.x, t = threadIdx.x;
    if (b < SB_EDGE) {                       // attr: 262144 exact
        int i = b * NT + t;
        int r = attr_row[i];
        unsigned pos = atomicAdd(&cnt[r << 4], 1u);   // padded: 1 counter / 64B line
        if (pos < ASTR) ccol[(size_t)r * ASTR + pos] = (unsigned)attr_col[i];
    } else if (b < SB_JA) {                  // edges -> ebt: 131072 exact
        int j = (b - SB_EDGE) * NT + t;
        int p = edge[j], q = edge[E_ + j];
        atomicOr(&ebt[(size_t)q * WORDS + (p >> 5)], 1u << (p & 31));
    } else if (b < SB_DIAG) {                // ja -> abt: 80000 guarded
        int j = (b - SB_JA) * NT + t;
        if (j < NNZ_JA) {
            int p = jaug[j], q = jaug[NNZ_JA + j];
            atomicOr(&abt[(size_t)q * WORDS + (p >> 5)], 1u << (p & 31));
        }
    } else {                                 // diag -> abt: 4096 exact
        int r = (b - SB_DIAG) * NT + t;
        atomicOr(&abt[(size_t)r * WORDS + (r >> 5)], 1u << (r & 31));
    }
}

// ---------------- K3: jm entries probe ebt; hits -> abt ----------------
__global__ void k_scat2(const int* __restrict__ jmsk,
                        const unsigned* __restrict__ ebt, unsigned* __restrict__ abt) {
    int i = blockIdx.x * NT + threadIdx.x;
    if (i >= NNZ_JM) return;
    int p = jmsk[i], q = jmsk[NNZ_JM + i];
    size_t w = (size_t)q * WORDS + (p >> 5);
    if ((ebt[w] >> (p & 31)) & 1u)
        atomicOr(&abt[w], 1u << (p & 31));
}

// ---------------- K4: abt row -> adj/dinv/deg, then h1s fp16 (4 rows/block) ----------------
__global__ void k_rowh1(const unsigned* __restrict__ abt, const unsigned* __restrict__ cnt,
                        const unsigned* __restrict__ ccol, const _Float16* __restrict__ w1t,
                        float* __restrict__ dinv, int* __restrict__ deg,
                        int* __restrict__ adj, _Float16* __restrict__ h1s) {
    __shared__ unsigned cols[128];
    __shared__ float part[4][2][32][8];   // 8 KB
    __shared__ float sdinv[4];
    const int b = blockIdx.x, t = threadIdx.x;
    int wv = t >> 6, lane = t & 63;
    int q = 4 * b + wv;
    {
        uint2 m2 = ((const uint2*)(abt + (size_t)q * WORDS))[lane];
        unsigned w0 = m2.x, w1b = m2.y;
        int c = __popc(w0) + __popc(w1b);
        int pre = c;
        #pragma unroll
        for (int d2 = 1; d2 < 64; d2 <<= 1) {
            int x = __shfl_up(pre, d2);
            if (lane >= d2) pre += x;
        }
        int excl = pre - c;
        int total = __shfl(pre, 63);
        if (lane == 0) {
            float dv = rsqrtf((float)total);
            dinv[q] = dv;
            sdinv[wv] = dv;
            deg[q] = total < ADJ_STRIDE ? total : ADJ_STRIDE;
        }
        unsigned idx = (unsigned)excl;
        int* arow = adj + (size_t)q * ADJ_STRIDE;
        int base0 = lane * 64;
        while (w0)  { int bp = __ffs(w0) - 1;  w0  &= w0 - 1;  if (idx < ADJ_STRIDE) arow[idx] = base0 + bp;      ++idx; }
        while (w1b) { int bp = __ffs(w1b) - 1; w1b &= w1b - 1; if (idx < ADJ_STRIDE) arow[idx] = base0 + 32 + bp; ++idx; }
    }
    __syncthreads();
    int g = t >> 6, hw = (t >> 5) & 1, l32 = t & 31;
    for (int i = 0; i < 4; ++i) {
        int r = 4 * b + i;
        int m = (int)min(cnt[r << 4], (unsigned)ASTR);
        if (t < m) cols[t] = ccol[(size_t)r * ASTR + t];
        __syncthreads();
        float acc[8];
        #pragma unroll
        for (int e = 0; e < 8; ++e) acc[e] = 0.f;
        int sub = (g << 1) + hw;             // 0..7: column slot within each 8-group
        for (int j = 0; j < m; j += 8) {
            int jc = j + sub;
            if (jc < m) {
                unsigned c = cols[jc];
                half8v v = *(const half8v*)(w1t + (size_t)c * H_ + l32 * 8);
                #pragma unroll
                for (int e = 0; e < 8; ++e) acc[e] += (float)v[e];
            }
        }
        #pragma unroll
        for (int e = 0; e < 8; ++e) part[g][hw][l32][e] = acc[e];
        __syncthreads();
        // thread t reduces H-element t over the 8 (g,hw) partials
        int l = t >> 3, e = t & 7;
        float s = 0.f;
        #pragma unroll
        for (int gg = 0; gg < 4; ++gg) {
            s += part[gg][0][l][e];
            s += part[gg][1][l][e];
        }
        h1s[(size_t)r * H_ + t] = (_Float16)(s * sdinv[i]);
        __syncthreads();
    }
}

// ---------------- K5: out1 = relu(dinv*sum_adj h1s); h2s = dinv*(out1 @ W2^T) ----------------
__global__ void k_prop1(const int* __restrict__ adj, const int* __restrict__ deg,
                        const float* __restrict__ dinv, const _Float16* __restrict__ h1s,
                        const float* __restrict__ w2, float* __restrict__ h2s) {
    __shared__ int adj_s[128];
    __shared__ float partial2[2][256];   // 2 KB
    __shared__ float hrow[256];
    __shared__ float partial[16][17];
    const int b = blockIdx.x, t = threadIdx.x;
    int g2 = t >> 7, tt = t & 127;       // half-block x 128 element-pairs
    int c = t & 15, gg = t >> 4;
    float w2r[16];
    #pragma unroll
    for (int kk = 0; kk < 16; ++kk) w2r[kk] = w2[(size_t)c * H_ + gg * 16 + kk];
    for (int i = 0; i < 4; ++i) {
        int q = 4 * b + i;
        __syncthreads();
        if (t < ADJ_STRIDE) adj_s[t] = adj[(size_t)q * ADJ_STRIDE + t];
        __syncthreads();
        int dg = deg[q];
        float ax = 0.f, ay = 0.f;
        int j = g2;
        for (; j + 2 < dg; j += 4) {
            int p0 = adj_s[j], p1 = adj_s[j + 2];
            half2v v0 = *(const half2v*)(h1s + (size_t)p0 * H_ + tt * 2);
            half2v v1 = *(const half2v*)(h1s + (size_t)p1 * H_ + tt * 2);
            ax += (float)v0[0] + (float)v1[0];
            ay += (float)v0[1] + (float)v1[1];
        }
        for (; j < dg; j += 2) {
            int p0 = adj_s[j];
            half2v v0 = *(const half2v*)(h1s + (size_t)p0 * H_ + tt * 2);
            ax += (float)v0[0];
            ay += (float)v0[1];
        }
        partial2[g2][2 * tt]     = ax;
        partial2[g2][2 * tt + 1] = ay;
        __syncthreads();
        float dq = dinv[q];
        hrow[t] = fmaxf((partial2[0][t] + partial2[1][t]) * dq, 0.f);
        __syncthreads();
        float p = 0.f;
        #pragma unroll
        for (int kk = 0; kk < 16; ++kk) p += hrow[gg * 16 + kk] * w2r[kk];
        partial[gg][c] = p;
        __syncthreads();
        if (t < 16) {
            float s = 0.f;
            #pragma unroll
            for (int g3 = 0; g3 < 16; ++g3) s += partial[g3][t];
            h2s[(size_t)q * C_ + t] = s * dq;
        }
    }
}

// ---------------- K6: out[q,c] = dinv[q]*sum_adj h2s[p,c] + bias[c] ----------------
__global__ void k_prop2(const int* __restrict__ adj, const int* __restrict__ deg,
                        const float* __restrict__ dinv, const float* __restrict__ h2s,
                        const float* __restrict__ bias, float* __restrict__ out) {
    const int b = blockIdx.x, t = threadIdx.x;
    int wv = t >> 6, lane = t & 63;
    int q = 4 * b + wv;
    int c = lane & 15, prt = lane >> 4;
    int dg = deg[q];
    const int* arow = adj + (size_t)q * ADJ_STRIDE;
    float acc = 0.f;
    for (int j = prt; j < dg; j += 4)
        acc += h2s[(size_t)arow[j] * C_ + c];
    acc += __shfl_down(acc, 32);
    acc += __shfl_down(acc, 16);
    if (lane < 16)
        out[(size_t)q * C_ + c] = dinv[q] * acc + bias[c];
}

// ---------------- launch ----------------

extern "C" void kernel_launch(void* const* d_in, const int* in_sizes, int n_in,
                              void* d_out, int out_size, void* d_ws, size_t ws_size,
                              hipStream_t stream) {
    const int*   attr_row = (const int*)d_in[0];
    const int*   attr_col = (const int*)d_in[1];
    const int*   edge     = (const int*)d_in[2];   // [2][E_]
    const int*   jmsk     = (const int*)d_in[3];   // [2][NNZ_JM]
    const int*   jaug     = (const int*)d_in[4];   // [2][NNZ_JA]
    const float* w1       = (const float*)d_in[5]; // [H_][D_]
    const float* w2       = (const float*)d_in[6]; // [C_][H_]
    const float* bias2    = (const float*)d_in[7]; // [C_]
    float*       out      = (float*)d_out;

    char* ws = (char*)d_ws;
    unsigned*  ebt  = (unsigned*)(ws + OFF_EBT);
    unsigned*  abt  = (unsigned*)(ws + OFF_ABT);
    unsigned*  cnt  = (unsigned*)(ws + OFF_CNT);
    float*     dinv = (float*)(ws + OFF_DINV);
    int*       deg  = (int*)(ws + OFF_DEG);
    unsigned*  ccol = (unsigned*)(ws + OFF_CCOL);
    int*       adj  = (int*)(ws + OFF_ADJ);
    _Float16*  w1t  = (_Float16*)(ws + OFF_W1T);
    _Float16*  h1s  = (_Float16*)(ws + OFF_H1);
    float*     h2s  = (float*)(ws + OFF_H2);

    k_pre<<<ZB_BLOCKS + TR_BLOCKS, NT, 0, stream>>>(w1, w1t, (uint4*)d_ws);
    k_scat1<<<SB_TOTAL, NT, 0, stream>>>(attr_row, attr_col, edge, jaug,
                                         ebt, abt, cnt, ccol);
    k_scat2<<<(NNZ_JM + NT - 1) / NT, NT, 0, stream>>>(jmsk, ebt, abt);
    k_rowh1<<<N_ / 4, NT, 0, stream>>>(abt, cnt, ccol, w1t, dinv, deg, adj, h1s);
    k_prop1<<<N_ / 4, NT, 0, stream>>>(adj, deg, dinv, h1s, w2, h2s);
    k_prop2<<<N_ / 4, NT, 0, stream>>>(adj, deg, dinv, h2s, bias2, out);
}